// Round 2
// 642.769 us; speedup vs baseline: 1.3128x; 1.3128x over previous
//
#include <hip/hip_runtime.h>

#define NB 2
#define CIN 3
#define HH 512
#define WW 512
#define C2 64
#define HM 504   // mode-pool output size

typedef float v2f  __attribute__((ext_vector_type(2)));
typedef float v2fu __attribute__((ext_vector_type(2), aligned(4)));

// ---------------- K2: quantize (inline) + mode pool 11x11 -> u8 [2,3,504,504] ----------------
__global__ __launch_bounds__(256) void k_mode(const float* __restrict__ x,
                                              unsigned char* __restrict__ hmode) {
  __shared__ unsigned char tile[26 * 26];
  int bc  = blockIdx.z;
  int ty0 = blockIdx.y * 16, tx0 = blockIdx.x * 16;
  const float* src = x + (size_t)bc * HH * WW;
  for (int i = threadIdx.x; i < 26 * 26; i += 256) {
    int r = i / 26, cl = i % 26;
    int Y = ty0 + r, X = tx0 + cl;      // padded coords (pad=1)
    unsigned char v = 0;
    if (Y >= 1 && Y <= HH && X >= 1 && X <= WW) {
      float val = src[(Y - 1) * WW + (X - 1)];
      float q = rintf((val * 255.0f) / 16.0f);   // matches jnp.round(x*255/16), RNE
      q = fminf(fmaxf(q, 0.0f), 16.0f);
      v = (unsigned char)(int)q;
    }
    tile[i] = v;
  }
  __syncthreads();
  int ty = threadIdx.x >> 4, tx = threadIdx.x & 15;
  int oy = ty0 + ty, ox = tx0 + tx;
  if (oy >= HM || ox >= HM) return;
  unsigned long long w0 = 0, w1 = 0, w2 = 0;
  for (int dy = 0; dy < 11; dy++) {
    #pragma unroll
    for (int dx = 0; dx < 11; dx++) {
      int b = tile[(ty + dy) * 26 + tx + dx];
      unsigned long long inc = 1ull << ((b & 7) * 8);
      if (b < 8) w0 += inc;
      else if (b < 16) w1 += inc;
      else w2 += inc;
    }
  }
  int best = -1, bestb = 0;
  #pragma unroll
  for (int b = 0; b < 17; b++) {
    int cnt;
    if (b < 8)       cnt = (int)((w0 >> (b * 8)) & 0xff);
    else if (b < 16) cnt = (int)((w1 >> ((b - 8) * 8)) & 0xff);
    else             cnt = (int)(w2 & 0xff);
    if (cnt > best) { best = cnt; bestb = b; }   // strict > keeps lowest bin on tie
  }
  hmode[bc * HM * HM + oy * HM + ox] = (unsigned char)bestb;
}

// ---------------- K3: fused conv1+maxleaky + grouped conv2 + minleaky + downgrade ----------------
__global__ __launch_bounds__(256) void k_prepare(const unsigned char* __restrict__ hmode,
                                                 const float* __restrict__ w1,
                                                 const float* __restrict__ b1,
                                                 const float* __restrict__ w2,
                                                 const float* __restrict__ b2,
                                                 const float* __restrict__ down_k,
                                                 const float* __restrict__ down_b,
                                                 float* __restrict__ d1) {
  int bc = blockIdx.y;
  int b  = bc >> 6;
  int c  = bc & 63;
  int pix = blockIdx.x * 256 + threadIdx.x;
  if (pix >= 168 * 168) return;
  int oy = pix / 168, ox = pix % 168;
  int c0 = (c >> 1) << 1;
  float w1a0 = w1[c0 * 3], w1a1 = w1[c0 * 3 + 1], w1a2 = w1[c0 * 3 + 2], b1a = b1[c0];
  float w1b0 = w1[(c0 + 1) * 3], w1b1 = w1[(c0 + 1) * 3 + 1], w1b2 = w1[(c0 + 1) * 3 + 2], b1b = b1[c0 + 1];
  float w2a = w2[c * 2], w2b = w2[c * 2 + 1], b2c = b2[c];
  float kb = *down_b;
  const unsigned char* h0p = hmode + (b * 3 + 0) * HM * HM;
  const unsigned char* h1p = hmode + (b * 3 + 1) * HM * HM;
  const unsigned char* h2p = hmode + (b * 3 + 2) * HM * HM;
  float acc = 0.0f;
  #pragma unroll
  for (int ky = 0; ky < 3; ky++) {
    int y = 3 * oy - 1 + ky;
    if (y < 0 || y >= HM) continue;
    #pragma unroll
    for (int kx = 0; kx < 3; kx++) {
      int xx = 3 * ox - 1 + kx;
      if (xx < 0 || xx >= HM) continue;
      int o = y * HM + xx;
      float hh0 = h0p[o] * (1.0f / 16.0f);
      float hh1 = h1p[o] * (1.0f / 16.0f);
      float hh2 = h2p[o] * (1.0f / 16.0f);
      float a0 = w1a0 * hh0 + w1a1 * hh1 + w1a2 * hh2 + b1a;
      float a1 = w1b0 * hh0 + w1b1 * hh1 + w1b2 * hh2 + b1b;
      a0 = (a0 <= 0.1f) ? a0 : 0.1f + 0.01f * (a0 - 0.1f);
      a1 = (a1 <= 0.1f) ? a1 : 0.1f + 0.01f * (a1 - 0.1f);
      float v = w2a * a0 + w2b * a1 + b2c;
      v = (v >= 0.1f) ? v : 0.1f + 0.01f * (v - 0.1f);
      acc += down_k[ky * 3 + kx] * v;
    }
  }
  float r = acc + kb;
  r = (r >= 0.0f) ? r : 0.01f * r;
  d1[bc * 168 * 168 + pix] = r;
}

// ---------------- K4: generic downgrade (3x3 s3 p1 shared) + leaky ----------------
__global__ __launch_bounds__(256) void k_down(const float* __restrict__ din,
                                              float* __restrict__ dout,
                                              const float* __restrict__ down_k,
                                              const float* __restrict__ down_b,
                                              int S, int So) {
  int bc = blockIdx.y;
  int pix = blockIdx.x * 256 + threadIdx.x;
  if (pix >= So * So) return;
  int oy = pix / So, ox = pix % So;
  const float* p = din + bc * S * S;
  float acc = 0.0f;
  #pragma unroll
  for (int ky = 0; ky < 3; ky++) {
    int y = 3 * oy - 1 + ky;
    if (y < 0 || y >= S) continue;
    #pragma unroll
    for (int kx = 0; kx < 3; kx++) {
      int xx = 3 * ox - 1 + kx;
      if (xx < 0 || xx >= S) continue;
      acc += down_k[ky * 3 + kx] * p[y * S + xx];
    }
  }
  float r = acc + *down_b;
  r = (r >= 0.0f) ? r : 0.01f * r;
  dout[bc * So * So + pix] = r;
}

// ---------------- K_lut: packed bilinear LUT {asfloat(y0), w} per level/coord ----------------
__global__ __launch_bounds__(256) void k_lut(float2* __restrict__ lutpk) {
  int idx = blockIdx.x * 256 + threadIdx.x;   // 5*512
  if (idx >= 5 * 512) return;
  int lvl = idx >> 9, Y = idx & 511;
  const int Ls[5] = {168, 56, 19, 7, 3};
  int L = Ls[lvl];
  float f = (Y + 0.5f) * ((float)L / 512.0f) - 0.5f;
  f = fminf(fmaxf(f, 0.0f), (float)(L - 1));
  int y0 = (int)f;
  float w = f - (float)y0;
  lutpk[idx] = make_float2(__int_as_float(y0), w);
}

// ---------------- K5: fused 5-level resize + 5x5 shared conv + BN + leaky + sum ----------------
// Two-phase separable resize through LDS:
//   phase A: rowIT[x][r] = x-interp of source row r at output col x  (from global d)
//   phase B: z[y][x]     = y-interp of rowIT pairs
// phase A of level l+1 is co-issued with conv(l) (disjoint LDS) to hide global latency.
__global__ __launch_bounds__(256, 2) void k_score(const float* __restrict__ d1,
                                                  const float* __restrict__ d2,
                                                  const float* __restrict__ d3,
                                                  const float* __restrict__ d4,
                                                  const float* __restrict__ d5,
                                                  const float2* __restrict__ lutpk,
                                                  const float* __restrict__ interp_k,
                                                  const float* __restrict__ interp_b,
                                                  const float* __restrict__ i_gamma,
                                                  const float* __restrict__ i_beta,
                                                  const float* __restrict__ i_mean,
                                                  const float* __restrict__ i_var,
                                                  float* __restrict__ score) {
  __shared__ float z[68 * 68];
  __shared__ float rowIT[68 * 25];     // transposed: [x][r], stride 25
  __shared__ float2 lyp[68];           // {asfloat(a0rel), wy}

  int bc = blockIdx.y;
  int c  = bc & 63;
  int tile = blockIdx.x;
  int tyi = tile >> 3, txi = tile & 7;
  int ty0 = tyi * 64, tx0 = txi * 64;
  bool interior = (tyi >= 1 && tyi <= 6 && txi >= 1 && txi <= 6);
  float K[25];
  #pragma unroll
  for (int i = 0; i < 25; i++)
    K[i] = __int_as_float(__builtin_amdgcn_readfirstlane(__float_as_int(interp_k[i])));
  float ib  = __int_as_float(__builtin_amdgcn_readfirstlane(__float_as_int(*interp_b)));
  float isc = i_gamma[c] * rsqrtf(i_var[c] + 1e-5f);
  float ibe = i_beta[c] - i_mean[c] * isc;
  int tid = threadIdx.x;
  int oyl = (tid >> 4) << 2, oxl = (tid & 15) << 2;  // 4x4 px per thread
  float acc[4][4];
  #pragma unroll
  for (int i = 0; i < 4; i++)
    #pragma unroll
    for (int j = 0; j < 4; j++) acc[i][j] = 0.0f;

  const float* dls[5] = {d1, d2, d3, d4, d5};
  const int Ls[5]  = {168, 56, 19, 7, 3};
  const int RLs[5] = {24, 10, 5, 3, 3};

  auto phaseA = [&](int l) {
    int L = Ls[l], R = RLs[l];
    const float* dp = dls[l] + bc * L * L;
    const float2* lp = lutpk + (l << 9);
    int Ylo = max(ty0 - 2, 0);
    int r0 = __float_as_int(lp[Ylo].x);
    if (tid < 68) {
      int Yc = min(max(ty0 - 2 + tid, 0), 511);
      float2 pk = lp[Yc];
      lyp[tid] = make_float2(__int_as_float(__float_as_int(pk.x) - r0), pk.y);
    }
    for (int i = tid; i < R * 68; i += 256) {
      int r = i / 68, xx = i - r * 68;
      int Xc = min(max(tx0 - 2 + xx, 0), 511);
      float2 pk = lp[Xc];
      int ix = __float_as_int(pk.x);
      float wx = pk.y;
      int gr = min(r0 + r, L - 1);
      const float* rp = dp + gr * L + ix;
      float v0 = rp[0], v1 = rp[1];       // v1 unused when wx==0 (clamp)
      rowIT[xx * 25 + r] = v0 + wx * (v1 - v0);
    }
  };

  auto phaseB = [&]() {
    if (interior) {
      for (int i = tid; i < 68 * 68; i += 256) {
        int yy = i / 68, xx = i - yy * 68;
        float2 pk = lyp[yy];
        int a0 = __float_as_int(pk.x);
        const float* rp = &rowIT[xx * 25 + a0];
        float rA = rp[0], rB = rp[1];
        z[i] = rA + pk.y * (rB - rA);
      }
    } else {
      for (int i = tid; i < 68 * 68; i += 256) {
        int yy = i / 68, xx = i - yy * 68;
        float2 pk = lyp[yy];
        int a0 = __float_as_int(pk.x);
        const float* rp = &rowIT[xx * 25 + a0];
        float rA = rp[0], rB = rp[1];
        float v = rA + pk.y * (rB - rA);
        int Y = ty0 - 2 + yy, X = tx0 - 2 + xx;
        if (Y < 0 || Y >= 512 || X < 0 || X >= 512) v = 0.0f;
        z[i] = v;
      }
    }
  };

  auto convAcc = [&]() {
    v2f t2[4][2];
    #pragma unroll
    for (int i = 0; i < 4; i++) { t2[i][0] = (v2f)0.0f; t2[i][1] = (v2f)0.0f; }
    #pragma unroll
    for (int iy = 0; iy < 8; iy++) {
      const float4 za = *(const float4*)&z[(oyl + iy) * 68 + oxl];
      const float4 zb = *(const float4*)&z[(oyl + iy) * 68 + oxl + 4];
      v2f qq[7];
      qq[0].x = za.x; qq[0].y = za.y;
      qq[1].x = za.y; qq[1].y = za.z;
      qq[2].x = za.z; qq[2].y = za.w;
      qq[3].x = za.w; qq[3].y = zb.x;
      qq[4].x = zb.x; qq[4].y = zb.y;
      qq[5].x = zb.y; qq[5].y = zb.z;
      qq[6].x = zb.z; qq[6].y = zb.w;
      #pragma unroll
      for (int ky = 0; ky < 5; ky++) {
        const int o = iy - ky;
        if (o >= 0 && o < 4) {
          #pragma unroll
          for (int kx = 0; kx < 5; kx++) {
            float kv = K[ky * 5 + kx];
            v2f kk; kk.x = kv; kk.y = kv;
            t2[o][0] += kk * qq[kx];
            t2[o][1] += kk * qq[kx + 2];
          }
        }
      }
    }
    #pragma unroll
    for (int i = 0; i < 4; i++) {
      float tv[4] = {t2[i][0].x, t2[i][0].y, t2[i][1].x, t2[i][1].y};
      #pragma unroll
      for (int j = 0; j < 4; j++) {
        float v = (tv[j] + ib) * isc + ibe;
        v = (v >= 0.0f) ? v : 0.01f * v;
        acc[i][j] += v;
      }
    }
  };

  phaseA(0);
  __syncthreads();
  phaseB();
  #pragma unroll 1
  for (int l = 0; l < 5; l++) {
    __syncthreads();                 // z(l) ready; rowIT/lyp consumed
    if (l < 4) phaseA(l + 1);        // global->rowIT, overlaps conv
    convAcc();                       // reads z(l)
    __syncthreads();                 // conv done with z; rowIT(l+1) ready
    if (l < 4) phaseB();             // rowIT->z(l+1)
  }

  float* op = score + bc * 512 * 512;
  #pragma unroll
  for (int i = 0; i < 4; i++) {
    int Y = ty0 + oyl + i;
    float4 vv = make_float4(acc[i][0], acc[i][1], acc[i][2], acc[i][3]);
    *(float4*)(op + Y * 512 + tx0 + oxl) = vv;
  }
}

// ---------------- K6: 3x ft as a full-row-width vertical pipeline ----------------
// Each block owns all 512 columns (256 thr x 2 cols, float2) of one (b,c) slice,
// for a 128-row output band. The three emphase iterations run as pipeline stages
// staggered 6 rows apart (total depth 17). Per stage:
//   U_s = Aff*S_{s-1} + Cc          (stage 1 reads global s0; stages 2,3 read LDS rings)
//   C_s(y) = C_s(y-1) + U_s(y+5) - U_s(y-6)   (incremental column sum, register)
//   brow_s <- C_s row               (LDS row buffer, +-6 zero pads)
//   S_s(y) = (1+w)*U_s(y) - (w/121)*rowsum11(brow_s)
// No horizontal halo, no tile overcompute (just 32 warm-up steps per 128-row band).
// All LDS accesses are lane-stride-2 float2 -> conflict-free.
// Warm-up: incremental-sum garbage cancels by telescoping (finite values only);
// subtract/center reads are masked by (row >= mstart - stage_offset) so rows never
// added (or uninitialized ring slots) are treated as 0.
__global__ __launch_bounds__(256, 2) void k_ft_pipe(const float* __restrict__ s_in,
                                                    float* __restrict__ s_out,
                                                    const float* __restrict__ ft_gamma,
                                                    const float* __restrict__ ft_beta,
                                                    const float* __restrict__ ft_mean,
                                                    const float* __restrict__ ft_var,
                                                    const float* __restrict__ ft_k,
                                                    const float* __restrict__ ft_b,
                                                    const float* __restrict__ emph_w) {
  __shared__ float ring2[12 * 512];   // U2 rows (affine-applied), per-thread columns only
  __shared__ float ring3[12 * 512];   // U3 rows
  __shared__ float brow1[528];        // C1 row, idx = col + 6, pads [0..5],[518..523] = 0
  __shared__ float brow2[528];
  __shared__ float brow3[528];

  const int bc = blockIdx.y;          // 0..127
  const int c  = bc & 63;
  const int R0 = blockIdx.x << 7;     // band start row (0,128,256,384)
  const int mstart = R0 - 15;

  const float sc  = ft_gamma[c] * rsqrtf(ft_var[c] + 1e-5f);
  const float fk = *ft_k, fb = *ft_b;
  const float Aff = sc * fk;
  const float Cc  = (ft_beta[c] - ft_mean[c] * sc) * fk + fb;
  const float w   = emph_w[c];
  const float opw = 1.0f + w;
  const float okw = w * (1.0f / 121.0f);

  const int tid = threadIdx.x;
  const int x0  = tid << 1;

  const float* sp = s_in + ((size_t)bc << 18) + x0;
  float*       op = s_out + ((size_t)bc << 18) + x0;

  // zero the horizontal pads once (ordered before first read by the in-loop barrier)
  if (tid < 12) {
    int p = (tid < 6) ? tid : (512 + tid);
    brow1[p] = 0.0f; brow2[p] = 0.0f; brow3[p] = 0.0f;
  }

  auto ldraw = [&](int row) -> v2f {
    int rc = min(max(row, 0), 511);        // clamp keeps the access in-bounds
    return *(const v2f*)(sp + ((size_t)rc << 9));
  };

  // two 11-sums (cols x0, x0+1) from brow window [x0-6 .. x0+7]
  auto rowsum = [&](const float* b) -> v2f {
    const float* p = b + x0;               // brow idx x0 == col x0-6
    v2f w0 = *(const v2f*)(p);
    v2f w1 = *(const v2f*)(p + 2);
    v2f w2 = *(const v2f*)(p + 4);
    v2f w3 = *(const v2f*)(p + 6);
    v2f w4 = *(const v2f*)(p + 8);
    v2f w5 = *(const v2f*)(p + 10);
    v2f w6 = *(const v2f*)(p + 12);
    float smid = ((w1.x + w1.y) + (w2.x + w2.y)) +
                 ((w3.x + w3.y) + (w4.x + w4.y)) + (w5.x + w5.y);   // cols x0-4..x0+5
    v2f r;
    r.x = smid + w0.y;   // + col x0-5
    r.y = smid + w6.x;   // + col x0+6
    return r;
  };

  v2f cs1 = (v2f)0.0f, cs2 = (v2f)0.0f, cs3 = (v2f)0.0f;
  v2f out1p = (v2f)0.0f, out2p = (v2f)0.0f;   // S1/S2 rows produced last step (raw)

  int m = mstart;
  v2f gf = ldraw(m);          // row m      (stage-1 front)
  v2f go = ldraw(m - 11);     // row m-11   (stage-1 subtract)
  v2f gc = ldraw(m - 5);      // row m-5    (stage-1 center)
  int sw = 0;                 // i % 12

  #pragma unroll 1
  for (int i = 0; i < 160; ++i, ++m) {
    // software prefetch for next step (hides HBM/L2 latency across the two barriers)
    v2f gf_n = ldraw(m + 1);
    v2f go_n = ldraw(m - 10);
    v2f gc_n = ldraw(m - 4);

    int swn = (sw + 1 == 12) ? 0 : sw + 1;        // slot holding row (front-11)
    int swc = (sw + 7 >= 12) ? sw - 5 : sw + 7;   // slot holding row (front-5)

    // ---------------- W phase: advance column sums, publish C rows ----------------
    {  // stage 1: front row m
      v2f u1f = (m >= 0 && m < 512) ? (gf * Aff + Cc) : (v2f)0.0f;
      int r = m - 11;
      v2f u1o = (r >= mstart && r >= 0 && r < 512) ? (go * Aff + Cc) : (v2f)0.0f;
      cs1 += u1f - u1o;                            // cs1 = colsum at row m-5
      *(v2f*)(brow1 + 6 + x0) = cs1;
    }
    {  // stage 2: front row m-6 (consumes out1p = S1(m-6))
      v2f u2s = out1p * Aff + Cc;
      *(v2f*)(ring2 + sw * 512 + x0) = u2s;
      int rf = m - 6;
      v2f u2f = (rf >= 0 && rf < 512) ? u2s : (v2f)0.0f;
      int r = m - 17;
      v2f u2or = *(const v2f*)(ring2 + swn * 512 + x0);
      v2f u2o = (r >= mstart - 6 && r >= 0 && r < 512) ? u2or : (v2f)0.0f;
      cs2 += u2f - u2o;                            // cs2 = colsum at row m-11
      *(v2f*)(brow2 + 6 + x0) = cs2;
    }
    {  // stage 3: front row m-12 (consumes out2p = S2(m-12))
      v2f u3s = out2p * Aff + Cc;
      *(v2f*)(ring3 + sw * 512 + x0) = u3s;
      int rf = m - 12;
      v2f u3f = (rf >= 0 && rf < 512) ? u3s : (v2f)0.0f;
      int r = m - 23;
      v2f u3or = *(const v2f*)(ring3 + swn * 512 + x0);
      v2f u3o = (r >= mstart - 12 && r >= 0 && r < 512) ? u3or : (v2f)0.0f;
      cs3 += u3f - u3o;                            // cs3 = colsum at row m-17
      *(v2f*)(brow3 + 6 + x0) = cs3;
    }
    __syncthreads();
    // ---------------- R phase: horizontal 11-sums, emit stage outputs ----------------
    {  // S1(m-5)
      int rc1 = m - 5;
      v2f u1c = (rc1 >= 0 && rc1 < 512) ? (gc * Aff + Cc) : (v2f)0.0f;
      v2f B1 = rowsum(brow1);
      out1p = u1c * opw - B1 * okw;
    }
    {  // S2(m-11)
      int rc2 = m - 11;
      v2f u2cr = *(const v2f*)(ring2 + swc * 512 + x0);
      v2f u2c = (rc2 >= mstart - 6 && rc2 >= 0 && rc2 < 512) ? u2cr : (v2f)0.0f;
      v2f B2 = rowsum(brow2);
      out2p = u2c * opw - B2 * okw;
    }
    {  // S3(m-17) -> global
      int rc3 = m - 17;
      v2f u3cr = *(const v2f*)(ring3 + swc * 512 + x0);
      v2f u3c = (rc3 >= mstart - 12 && rc3 >= 0 && rc3 < 512) ? u3cr : (v2f)0.0f;
      v2f B3 = rowsum(brow3);
      v2f o3 = u3c * opw - B3 * okw;
      if (i >= 32)
        *(v2f*)(op + ((size_t)(m - 17) << 9)) = o3;   // rows R0 .. R0+127
    }
    __syncthreads();
    gf = gf_n; go = go_n; gc = gc_n;
    sw = swn;
  }
}

extern "C" void kernel_launch(void* const* d_in, const int* in_sizes, int n_in,
                              void* d_out, int out_size, void* d_ws, size_t ws_size,
                              hipStream_t stream) {
  const float* x        = (const float*)d_in[0];
  const float* w1       = (const float*)d_in[1];
  const float* b1       = (const float*)d_in[2];
  const float* w2       = (const float*)d_in[3];
  const float* b2       = (const float*)d_in[4];
  const float* down_k   = (const float*)d_in[5];
  const float* down_b   = (const float*)d_in[6];
  const float* ft_gamma = (const float*)d_in[7];
  const float* ft_beta  = (const float*)d_in[8];
  const float* ft_mean  = (const float*)d_in[9];
  const float* ft_var   = (const float*)d_in[10];
  const float* ft_k     = (const float*)d_in[11];
  const float* ft_b     = (const float*)d_in[12];
  const float* emph_w   = (const float*)d_in[13];
  const float* interp_k = (const float*)d_in[14];
  const float* interp_b = (const float*)d_in[15];
  const float* i_gamma  = (const float*)d_in[16];
  const float* i_beta   = (const float*)d_in[17];
  const float* i_mean   = (const float*)d_in[18];
  const float* i_var    = (const float*)d_in[19];
  float* out = (float*)d_out;                    // [2,64,512,512]

  char* ws = (char*)d_ws;
  size_t off = 0;
  auto alloc = [&](size_t bytes) { size_t r = off; off += (bytes + 255) & ~(size_t)255; return r; };
  unsigned char* hmode = (unsigned char*)(ws + alloc((size_t)NB * CIN * HM * HM));
  float* d1 = (float*)(ws + alloc((size_t)NB * C2 * 168 * 168 * 4));
  float* d2 = (float*)(ws + alloc((size_t)NB * C2 * 56 * 56 * 4));
  float* d3 = (float*)(ws + alloc((size_t)NB * C2 * 19 * 19 * 4));
  float* d4 = (float*)(ws + alloc((size_t)NB * C2 * 7 * 7 * 4));
  float* d5 = (float*)(ws + alloc((size_t)NB * C2 * 3 * 3 * 4));
  float* s0 = (float*)(ws + alloc((size_t)NB * C2 * 512 * 512 * 4));  // pre-ft score
  float2* lutpk = (float2*)(ws + alloc((size_t)5 * 512 * 8));

  k_mode<<<dim3(32, 32, NB * CIN), 256, 0, stream>>>(x, hmode);
  k_lut<<<10, 256, 0, stream>>>(lutpk);
  k_prepare<<<dim3((168 * 168 + 255) / 256, NB * C2), 256, 0, stream>>>(
      hmode, w1, b1, w2, b2, down_k, down_b, d1);
  k_down<<<dim3((56 * 56 + 255) / 256, NB * C2), 256, 0, stream>>>(d1, d2, down_k, down_b, 168, 56);
  k_down<<<dim3((19 * 19 + 255) / 256, NB * C2), 256, 0, stream>>>(d2, d3, down_k, down_b, 56, 19);
  k_down<<<dim3((7 * 7 + 255) / 256, NB * C2), 256, 0, stream>>>(d3, d4, down_k, down_b, 19, 7);
  k_down<<<dim3((3 * 3 + 255) / 256, NB * C2), 256, 0, stream>>>(d4, d5, down_k, down_b, 7, 3);
  k_score<<<dim3(64, NB * C2), 256, 0, stream>>>(d1, d2, d3, d4, d5, lutpk,
                                                 interp_k, interp_b,
                                                 i_gamma, i_beta, i_mean, i_var, s0);
  k_ft_pipe<<<dim3(4, NB * C2), 256, 0, stream>>>(s0, out, ft_gamma, ft_beta, ft_mean,
                                                  ft_var, ft_k, ft_b, emph_w);
}

// Round 3
// 582.257 us; speedup vs baseline: 1.4492x; 1.1039x over previous
//
#include <hip/hip_runtime.h>

#define NB 2
#define CIN 3
#define HH 512
#define WW 512
#define C2 64
#define HM 504   // mode-pool output size

typedef float v2f  __attribute__((ext_vector_type(2)));
typedef float v2fu __attribute__((ext_vector_type(2), aligned(4)));

// ---------------- K2: quantize (inline) + mode pool 11x11 -> u8 [2,3,504,504] ----------------
__global__ __launch_bounds__(256) void k_mode(const float* __restrict__ x,
                                              unsigned char* __restrict__ hmode) {
  __shared__ unsigned char tile[26 * 26];
  int bc  = blockIdx.z;
  int ty0 = blockIdx.y * 16, tx0 = blockIdx.x * 16;
  const float* src = x + (size_t)bc * HH * WW;
  for (int i = threadIdx.x; i < 26 * 26; i += 256) {
    int r = i / 26, cl = i % 26;
    int Y = ty0 + r, X = tx0 + cl;      // padded coords (pad=1)
    unsigned char v = 0;
    if (Y >= 1 && Y <= HH && X >= 1 && X <= WW) {
      float val = src[(Y - 1) * WW + (X - 1)];
      float q = rintf((val * 255.0f) / 16.0f);   // matches jnp.round(x*255/16), RNE
      q = fminf(fmaxf(q, 0.0f), 16.0f);
      v = (unsigned char)(int)q;
    }
    tile[i] = v;
  }
  __syncthreads();
  int ty = threadIdx.x >> 4, tx = threadIdx.x & 15;
  int oy = ty0 + ty, ox = tx0 + tx;
  if (oy >= HM || ox >= HM) return;
  unsigned long long w0 = 0, w1 = 0, w2 = 0;
  for (int dy = 0; dy < 11; dy++) {
    #pragma unroll
    for (int dx = 0; dx < 11; dx++) {
      int b = tile[(ty + dy) * 26 + tx + dx];
      unsigned long long inc = 1ull << ((b & 7) * 8);
      if (b < 8) w0 += inc;
      else if (b < 16) w1 += inc;
      else w2 += inc;
    }
  }
  int best = -1, bestb = 0;
  #pragma unroll
  for (int b = 0; b < 17; b++) {
    int cnt;
    if (b < 8)       cnt = (int)((w0 >> (b * 8)) & 0xff);
    else if (b < 16) cnt = (int)((w1 >> ((b - 8) * 8)) & 0xff);
    else             cnt = (int)(w2 & 0xff);
    if (cnt > best) { best = cnt; bestb = b; }   // strict > keeps lowest bin on tie
  }
  hmode[bc * HM * HM + oy * HM + ox] = (unsigned char)bestb;
}

// ---------------- K3: fused conv1+maxleaky + grouped conv2 + minleaky + downgrade ----------------
__global__ __launch_bounds__(256) void k_prepare(const unsigned char* __restrict__ hmode,
                                                 const float* __restrict__ w1,
                                                 const float* __restrict__ b1,
                                                 const float* __restrict__ w2,
                                                 const float* __restrict__ b2,
                                                 const float* __restrict__ down_k,
                                                 const float* __restrict__ down_b,
                                                 float* __restrict__ d1) {
  int bc = blockIdx.y;
  int b  = bc >> 6;
  int c  = bc & 63;
  int pix = blockIdx.x * 256 + threadIdx.x;
  if (pix >= 168 * 168) return;
  int oy = pix / 168, ox = pix % 168;
  int c0 = (c >> 1) << 1;
  float w1a0 = w1[c0 * 3], w1a1 = w1[c0 * 3 + 1], w1a2 = w1[c0 * 3 + 2], b1a = b1[c0];
  float w1b0 = w1[(c0 + 1) * 3], w1b1 = w1[(c0 + 1) * 3 + 1], w1b2 = w1[(c0 + 1) * 3 + 2], b1b = b1[c0 + 1];
  float w2a = w2[c * 2], w2b = w2[c * 2 + 1], b2c = b2[c];
  float kb = *down_b;
  const unsigned char* h0p = hmode + (b * 3 + 0) * HM * HM;
  const unsigned char* h1p = hmode + (b * 3 + 1) * HM * HM;
  const unsigned char* h2p = hmode + (b * 3 + 2) * HM * HM;
  float acc = 0.0f;
  #pragma unroll
  for (int ky = 0; ky < 3; ky++) {
    int y = 3 * oy - 1 + ky;
    if (y < 0 || y >= HM) continue;
    #pragma unroll
    for (int kx = 0; kx < 3; kx++) {
      int xx = 3 * ox - 1 + kx;
      if (xx < 0 || xx >= HM) continue;
      int o = y * HM + xx;
      float hh0 = h0p[o] * (1.0f / 16.0f);
      float hh1 = h1p[o] * (1.0f / 16.0f);
      float hh2 = h2p[o] * (1.0f / 16.0f);
      float a0 = w1a0 * hh0 + w1a1 * hh1 + w1a2 * hh2 + b1a;
      float a1 = w1b0 * hh0 + w1b1 * hh1 + w1b2 * hh2 + b1b;
      a0 = (a0 <= 0.1f) ? a0 : 0.1f + 0.01f * (a0 - 0.1f);
      a1 = (a1 <= 0.1f) ? a1 : 0.1f + 0.01f * (a1 - 0.1f);
      float v = w2a * a0 + w2b * a1 + b2c;
      v = (v >= 0.1f) ? v : 0.1f + 0.01f * (v - 0.1f);
      acc += down_k[ky * 3 + kx] * v;
    }
  }
  float r = acc + kb;
  r = (r >= 0.0f) ? r : 0.01f * r;
  d1[bc * 168 * 168 + pix] = r;
}

// ---------------- K4: generic downgrade (3x3 s3 p1 shared) + leaky ----------------
__global__ __launch_bounds__(256) void k_down(const float* __restrict__ din,
                                              float* __restrict__ dout,
                                              const float* __restrict__ down_k,
                                              const float* __restrict__ down_b,
                                              int S, int So) {
  int bc = blockIdx.y;
  int pix = blockIdx.x * 256 + threadIdx.x;
  if (pix >= So * So) return;
  int oy = pix / So, ox = pix % So;
  const float* p = din + bc * S * S;
  float acc = 0.0f;
  #pragma unroll
  for (int ky = 0; ky < 3; ky++) {
    int y = 3 * oy - 1 + ky;
    if (y < 0 || y >= S) continue;
    #pragma unroll
    for (int kx = 0; kx < 3; kx++) {
      int xx = 3 * ox - 1 + kx;
      if (xx < 0 || xx >= S) continue;
      acc += down_k[ky * 3 + kx] * p[y * S + xx];
    }
  }
  float r = acc + *down_b;
  r = (r >= 0.0f) ? r : 0.01f * r;
  dout[bc * So * So + pix] = r;
}

// ---------------- K_lut: packed bilinear LUT {asfloat(y0), w} per level/coord ----------------
__global__ __launch_bounds__(256) void k_lut(float2* __restrict__ lutpk) {
  int idx = blockIdx.x * 256 + threadIdx.x;   // 5*512
  if (idx >= 5 * 512) return;
  int lvl = idx >> 9, Y = idx & 511;
  const int Ls[5] = {168, 56, 19, 7, 3};
  int L = Ls[lvl];
  float f = (Y + 0.5f) * ((float)L / 512.0f) - 0.5f;
  f = fminf(fmaxf(f, 0.0f), (float)(L - 1));
  int y0 = (int)f;
  float w = f - (float)y0;
  lutpk[idx] = make_float2(__int_as_float(y0), w);
}

// ---------------- K5: composite 5-level resize+conv+BN+leaky+sum ----------------
// Reformulation: conv rows commute with the vertical upsample, so
//   out[y][x] = sum_r conv5x(xrow[r], kappa[y][r])[x]
// where xrow[r] = x-upsampled coarse row r (68 wide, zero outside image) and
//   kappa[y][r][kx] = sum_ky vy(y,ky,r) * K[ky][kx]
// folds the bilinear y-weights into per-(row, coarse-row) 5-tap kernels.
// Vertical span: <=4 coarse rows (level 0), <=3 (levels 1-4). No z plane,
// no per-pixel y-lerp pass. Zero-pad semantics: OOB X -> xrow=0; OOB fine
// row -> ky skipped in kappa.
__global__ __launch_bounds__(256, 4) void k_score(const float* __restrict__ d1,
                                                  const float* __restrict__ d2,
                                                  const float* __restrict__ d3,
                                                  const float* __restrict__ d4,
                                                  const float* __restrict__ d5,
                                                  const float2* __restrict__ lutpk,
                                                  const float* __restrict__ interp_k,
                                                  const float* __restrict__ interp_b,
                                                  const float* __restrict__ i_gamma,
                                                  const float* __restrict__ i_beta,
                                                  const float* __restrict__ i_mean,
                                                  const float* __restrict__ i_var,
                                                  float* __restrict__ score) {
  __shared__ float xrow[24 * 68];      // [r][xx], stride 68 (272B, 16B-aligned rows)
  __shared__ float kap[64 * 4 * 8];    // [y][rrel][8] (5 used, padded for b128)
  __shared__ int   abase[64];          // a0base(y) - r0

  int bc = blockIdx.y;
  int c  = bc & 63;
  int tile = blockIdx.x;
  int tyi = tile >> 3, txi = tile & 7;
  int ty0 = tyi * 64, tx0 = txi * 64;
  float K[25];
  #pragma unroll
  for (int i = 0; i < 25; i++)
    K[i] = __int_as_float(__builtin_amdgcn_readfirstlane(__float_as_int(interp_k[i])));
  float ib  = __int_as_float(__builtin_amdgcn_readfirstlane(__float_as_int(*interp_b)));
  float isc = i_gamma[c] * rsqrtf(i_var[c] + 1e-5f);
  float ibe = i_beta[c] - i_mean[c] * isc;
  int tid = threadIdx.x;
  int oyl = (tid >> 4) << 2, oxl = (tid & 15) << 2;  // 4x4 px per thread
  float acc[4][4];
  #pragma unroll
  for (int i = 0; i < 4; i++)
    #pragma unroll
    for (int j = 0; j < 4; j++) acc[i][j] = 0.0f;

  const float* dls[5] = {d1, d2, d3, d4, d5};
  const int Ls[5]  = {168, 56, 19, 7, 3};
  const int RLs[5] = {24, 10, 5, 3, 3};

  auto fillLevel = [&](int l) {
    int L = Ls[l], RR = RLs[l];
    const float* dp = dls[l] + bc * L * L;
    const float2* lp = lutpk + (l << 9);
    int Ylo = max(ty0 - 2, 0);
    int r0 = __float_as_int(lp[Ylo].x);
    // kappa: thread tid -> (y = tid>>2, rrel = tid&3)
    {
      int y = tid >> 2, rr = tid & 3;
      int Y = ty0 + y;
      float kv0 = 0.0f, kv1 = 0.0f, kv2 = 0.0f, kv3 = 0.0f, kv4 = 0.0f;
      int ab = -1;
      #pragma unroll
      for (int ky = 0; ky < 5; ky++) {
        int yy = Y + ky - 2;
        if (yy >= 0 && yy < 512) {
          float2 pk = lp[yy];
          int a0 = __float_as_int(pk.x);
          float wv = pk.y;
          if (ab < 0) ab = a0;           // first valid ky has the min a0 (monotone)
          float cf = 0.0f;
          if (a0 - ab == rr)     cf += 1.0f - wv;
          if (a0 + 1 - ab == rr) cf += wv;
          kv0 += cf * K[ky * 5 + 0];
          kv1 += cf * K[ky * 5 + 1];
          kv2 += cf * K[ky * 5 + 2];
          kv3 += cf * K[ky * 5 + 3];
          kv4 += cf * K[ky * 5 + 4];
        }
      }
      float* kp = &kap[tid << 3];        // (y*4+rr)*8 == tid*8
      kp[0] = kv0; kp[1] = kv1; kp[2] = kv2; kp[3] = kv3; kp[4] = kv4;
      if (rr == 0) abase[y] = ab - r0;
    }
    // xrow: x-upsample coarse rows, zero outside image columns
    for (int i = tid; i < RR * 68; i += 256) {
      int r = i / 68, xx = i - r * 68;
      int X = tx0 - 2 + xx;
      float v = 0.0f;
      if (X >= 0 && X < 512) {
        float2 pk = lp[X];
        int ix = __float_as_int(pk.x);
        float wx = pk.y;
        int gr = min(r0 + r, L - 1);
        const float* rp = dp + gr * L + ix;
        float v0 = rp[0], v1 = rp[1];    // v1 unused when wx==0 (clamp)
        v = v0 + wx * (v1 - v0);
      }
      xrow[r * 68 + xx] = v;
    }
  };

  auto convAcc = [&](int rspan, int rlim) {
    #pragma unroll
    for (int i = 0; i < 4; i++) {
      int y = oyl + i;
      int ab = abase[y];
      float t0 = 0.0f, t1 = 0.0f, t2v = 0.0f, t3 = 0.0f;
      for (int rr = 0; rr < rspan; rr++) {
        int row = min(ab + rr, rlim);    // kappa==0 whenever clamp engages
        const float* xp = &xrow[row * 68 + oxl];
        float4 A = *(const float4*)xp;
        float4 B = *(const float4*)(xp + 4);
        const float* kp = &kap[(y << 5) + (rr << 3)];
        float k0 = kp[0], k1 = kp[1], k2 = kp[2], k3 = kp[3], k4 = kp[4];
        t0  += k0 * A.x + k1 * A.y + k2 * A.z + k3 * A.w + k4 * B.x;
        t1  += k0 * A.y + k1 * A.z + k2 * A.w + k3 * B.x + k4 * B.y;
        t2v += k0 * A.z + k1 * A.w + k2 * B.x + k3 * B.y + k4 * B.z;
        t3  += k0 * A.w + k1 * B.x + k2 * B.y + k3 * B.z + k4 * B.w;
      }
      float tv[4] = {t0, t1, t2v, t3};
      #pragma unroll
      for (int j = 0; j < 4; j++) {
        float v = (tv[j] + ib) * isc + ibe;
        v = (v >= 0.0f) ? v : 0.01f * v;
        acc[i][j] += v;
      }
    }
  };

  #pragma unroll 1
  for (int l = 0; l < 5; l++) {
    if (l) __syncthreads();              // conv(l-1) done with LDS
    fillLevel(l);
    __syncthreads();
    if (l == 0) convAcc(4, RLs[0] - 1);
    else        convAcc(3, RLs[l] - 1);
  }

  float* op = score + bc * 512 * 512;
  #pragma unroll
  for (int i = 0; i < 4; i++) {
    int Y = ty0 + oyl + i;
    float4 vv = make_float4(acc[i][0], acc[i][1], acc[i][2], acc[i][3]);
    *(float4*)(op + Y * 512 + tx0 + oxl) = vv;
  }
}

// ---------------- K6: 3x ft as a full-row-width vertical pipeline ----------------
// (unchanged from R2 — see that round's notes; next optimization target)
__global__ __launch_bounds__(256, 2) void k_ft_pipe(const float* __restrict__ s_in,
                                                    float* __restrict__ s_out,
                                                    const float* __restrict__ ft_gamma,
                                                    const float* __restrict__ ft_beta,
                                                    const float* __restrict__ ft_mean,
                                                    const float* __restrict__ ft_var,
                                                    const float* __restrict__ ft_k,
                                                    const float* __restrict__ ft_b,
                                                    const float* __restrict__ emph_w) {
  __shared__ float ring2[12 * 512];   // U2 rows (affine-applied), per-thread columns only
  __shared__ float ring3[12 * 512];   // U3 rows
  __shared__ float brow1[528];        // C1 row, idx = col + 6, pads [0..5],[518..523] = 0
  __shared__ float brow2[528];
  __shared__ float brow3[528];

  const int bc = blockIdx.y;          // 0..127
  const int c  = bc & 63;
  const int R0 = blockIdx.x << 7;     // band start row (0,128,256,384)
  const int mstart = R0 - 15;

  const float sc  = ft_gamma[c] * rsqrtf(ft_var[c] + 1e-5f);
  const float fk = *ft_k, fb = *ft_b;
  const float Aff = sc * fk;
  const float Cc  = (ft_beta[c] - ft_mean[c] * sc) * fk + fb;
  const float w   = emph_w[c];
  const float opw = 1.0f + w;
  const float okw = w * (1.0f / 121.0f);

  const int tid = threadIdx.x;
  const int x0  = tid << 1;

  const float* sp = s_in + ((size_t)bc << 18) + x0;
  float*       op = s_out + ((size_t)bc << 18) + x0;

  // zero the horizontal pads once (ordered before first read by the in-loop barrier)
  if (tid < 12) {
    int p = (tid < 6) ? tid : (512 + tid);
    brow1[p] = 0.0f; brow2[p] = 0.0f; brow3[p] = 0.0f;
  }

  auto ldraw = [&](int row) -> v2f {
    int rc = min(max(row, 0), 511);        // clamp keeps the access in-bounds
    return *(const v2f*)(sp + ((size_t)rc << 9));
  };

  // two 11-sums (cols x0, x0+1) from brow window [x0-6 .. x0+7]
  auto rowsum = [&](const float* b) -> v2f {
    const float* p = b + x0;               // brow idx x0 == col x0-6
    v2f w0 = *(const v2f*)(p);
    v2f w1 = *(const v2f*)(p + 2);
    v2f w2 = *(const v2f*)(p + 4);
    v2f w3 = *(const v2f*)(p + 6);
    v2f w4 = *(const v2f*)(p + 8);
    v2f w5 = *(const v2f*)(p + 10);
    v2f w6 = *(const v2f*)(p + 12);
    float smid = ((w1.x + w1.y) + (w2.x + w2.y)) +
                 ((w3.x + w3.y) + (w4.x + w4.y)) + (w5.x + w5.y);   // cols x0-4..x0+5
    v2f r;
    r.x = smid + w0.y;   // + col x0-5
    r.y = smid + w6.x;   // + col x0+6
    return r;
  };

  v2f cs1 = (v2f)0.0f, cs2 = (v2f)0.0f, cs3 = (v2f)0.0f;
  v2f out1p = (v2f)0.0f, out2p = (v2f)0.0f;   // S1/S2 rows produced last step (raw)

  int m = mstart;
  v2f gf = ldraw(m);          // row m      (stage-1 front)
  v2f go = ldraw(m - 11);     // row m-11   (stage-1 subtract)
  v2f gc = ldraw(m - 5);      // row m-5    (stage-1 center)
  int sw = 0;                 // i % 12

  #pragma unroll 1
  for (int i = 0; i < 160; ++i, ++m) {
    // software prefetch for next step (hides HBM/L2 latency across the two barriers)
    v2f gf_n = ldraw(m + 1);
    v2f go_n = ldraw(m - 10);
    v2f gc_n = ldraw(m - 4);

    int swn = (sw + 1 == 12) ? 0 : sw + 1;        // slot holding row (front-11)
    int swc = (sw + 7 >= 12) ? sw - 5 : sw + 7;   // slot holding row (front-5)

    // ---------------- W phase: advance column sums, publish C rows ----------------
    {  // stage 1: front row m
      v2f u1f = (m >= 0 && m < 512) ? (gf * Aff + Cc) : (v2f)0.0f;
      int r = m - 11;
      v2f u1o = (r >= mstart && r >= 0 && r < 512) ? (go * Aff + Cc) : (v2f)0.0f;
      cs1 += u1f - u1o;                            // cs1 = colsum at row m-5
      *(v2f*)(brow1 + 6 + x0) = cs1;
    }
    {  // stage 2: front row m-6 (consumes out1p = S1(m-6))
      v2f u2s = out1p * Aff + Cc;
      *(v2f*)(ring2 + sw * 512 + x0) = u2s;
      int rf = m - 6;
      v2f u2f = (rf >= 0 && rf < 512) ? u2s : (v2f)0.0f;
      int r = m - 17;
      v2f u2or = *(const v2f*)(ring2 + swn * 512 + x0);
      v2f u2o = (r >= mstart - 6 && r >= 0 && r < 512) ? u2or : (v2f)0.0f;
      cs2 += u2f - u2o;                            // cs2 = colsum at row m-11
      *(v2f*)(brow2 + 6 + x0) = cs2;
    }
    {  // stage 3: front row m-12 (consumes out2p = S2(m-12))
      v2f u3s = out2p * Aff + Cc;
      *(v2f*)(ring3 + sw * 512 + x0) = u3s;
      int rf = m - 12;
      v2f u3f = (rf >= 0 && rf < 512) ? u3s : (v2f)0.0f;
      int r = m - 23;
      v2f u3or = *(const v2f*)(ring3 + swn * 512 + x0);
      v2f u3o = (r >= mstart - 12 && r >= 0 && r < 512) ? u3or : (v2f)0.0f;
      cs3 += u3f - u3o;                            // cs3 = colsum at row m-17
      *(v2f*)(brow3 + 6 + x0) = cs3;
    }
    __syncthreads();
    // ---------------- R phase: horizontal 11-sums, emit stage outputs ----------------
    {  // S1(m-5)
      int rc1 = m - 5;
      v2f u1c = (rc1 >= 0 && rc1 < 512) ? (gc * Aff + Cc) : (v2f)0.0f;
      v2f B1 = rowsum(brow1);
      out1p = u1c * opw - B1 * okw;
    }
    {  // S2(m-11)
      int rc2 = m - 11;
      v2f u2cr = *(const v2f*)(ring2 + swc * 512 + x0);
      v2f u2c = (rc2 >= mstart - 6 && rc2 >= 0 && rc2 < 512) ? u2cr : (v2f)0.0f;
      v2f B2 = rowsum(brow2);
      out2p = u2c * opw - B2 * okw;
    }
    {  // S3(m-17) -> global
      int rc3 = m - 17;
      v2f u3cr = *(const v2f*)(ring3 + swc * 512 + x0);
      v2f u3c = (rc3 >= mstart - 12 && rc3 >= 0 && rc3 < 512) ? u3cr : (v2f)0.0f;
      v2f B3 = rowsum(brow3);
      v2f o3 = u3c * opw - B3 * okw;
      if (i >= 32)
        *(v2f*)(op + ((size_t)(m - 17) << 9)) = o3;   // rows R0 .. R0+127
    }
    __syncthreads();
    gf = gf_n; go = go_n; gc = gc_n;
    sw = swn;
  }
}

extern "C" void kernel_launch(void* const* d_in, const int* in_sizes, int n_in,
                              void* d_out, int out_size, void* d_ws, size_t ws_size,
                              hipStream_t stream) {
  const float* x        = (const float*)d_in[0];
  const float* w1       = (const float*)d_in[1];
  const float* b1       = (const float*)d_in[2];
  const float* w2       = (const float*)d_in[3];
  const float* b2       = (const float*)d_in[4];
  const float* down_k   = (const float*)d_in[5];
  const float* down_b   = (const float*)d_in[6];
  const float* ft_gamma = (const float*)d_in[7];
  const float* ft_beta  = (const float*)d_in[8];
  const float* ft_mean  = (const float*)d_in[9];
  const float* ft_var   = (const float*)d_in[10];
  const float* ft_k     = (const float*)d_in[11];
  const float* ft_b     = (const float*)d_in[12];
  const float* emph_w   = (const float*)d_in[13];
  const float* interp_k = (const float*)d_in[14];
  const float* interp_b = (const float*)d_in[15];
  const float* i_gamma  = (const float*)d_in[16];
  const float* i_beta   = (const float*)d_in[17];
  const float* i_mean   = (const float*)d_in[18];
  const float* i_var    = (const float*)d_in[19];
  float* out = (float*)d_out;                    // [2,64,512,512]

  char* ws = (char*)d_ws;
  size_t off = 0;
  auto alloc = [&](size_t bytes) { size_t r = off; off += (bytes + 255) & ~(size_t)255; return r; };
  unsigned char* hmode = (unsigned char*)(ws + alloc((size_t)NB * CIN * HM * HM));
  float* d1 = (float*)(ws + alloc((size_t)NB * C2 * 168 * 168 * 4));
  float* d2 = (float*)(ws + alloc((size_t)NB * C2 * 56 * 56 * 4));
  float* d3 = (float*)(ws + alloc((size_t)NB * C2 * 19 * 19 * 4));
  float* d4 = (float*)(ws + alloc((size_t)NB * C2 * 7 * 7 * 4));
  float* d5 = (float*)(ws + alloc((size_t)NB * C2 * 3 * 3 * 4));
  float* s0 = (float*)(ws + alloc((size_t)NB * C2 * 512 * 512 * 4));  // pre-ft score
  float2* lutpk = (float2*)(ws + alloc((size_t)5 * 512 * 8));

  k_mode<<<dim3(32, 32, NB * CIN), 256, 0, stream>>>(x, hmode);
  k_lut<<<10, 256, 0, stream>>>(lutpk);
  k_prepare<<<dim3((168 * 168 + 255) / 256, NB * C2), 256, 0, stream>>>(
      hmode, w1, b1, w2, b2, down_k, down_b, d1);
  k_down<<<dim3((56 * 56 + 255) / 256, NB * C2), 256, 0, stream>>>(d1, d2, down_k, down_b, 168, 56);
  k_down<<<dim3((19 * 19 + 255) / 256, NB * C2), 256, 0, stream>>>(d2, d3, down_k, down_b, 56, 19);
  k_down<<<dim3((7 * 7 + 255) / 256, NB * C2), 256, 0, stream>>>(d3, d4, down_k, down_b, 19, 7);
  k_down<<<dim3((3 * 3 + 255) / 256, NB * C2), 256, 0, stream>>>(d4, d5, down_k, down_b, 7, 3);
  k_score<<<dim3(64, NB * C2), 256, 0, stream>>>(d1, d2, d3, d4, d5, lutpk,
                                                 interp_k, interp_b,
                                                 i_gamma, i_beta, i_mean, i_var, s0);
  k_ft_pipe<<<dim3(4, NB * C2), 256, 0, stream>>>(s0, out, ft_gamma, ft_beta, ft_mean,
                                                  ft_var, ft_k, ft_b, emph_w);
}

// Round 4
// 576.589 us; speedup vs baseline: 1.4634x; 1.0098x over previous
//
#include <hip/hip_runtime.h>

#define NB 2
#define CIN 3
#define HH 512
#define WW 512
#define C2 64
#define HM 504   // mode-pool output size

typedef float v2f  __attribute__((ext_vector_type(2)));
typedef float v2fu __attribute__((ext_vector_type(2), aligned(4)));

// ---------------- K2: quantize (inline) + mode pool 11x11 -> u8 [2,3,504,504] ----------------
__global__ __launch_bounds__(256) void k_mode(const float* __restrict__ x,
                                              unsigned char* __restrict__ hmode) {
  __shared__ unsigned char tile[26 * 26];
  int bc  = blockIdx.z;
  int ty0 = blockIdx.y * 16, tx0 = blockIdx.x * 16;
  const float* src = x + (size_t)bc * HH * WW;
  for (int i = threadIdx.x; i < 26 * 26; i += 256) {
    int r = i / 26, cl = i % 26;
    int Y = ty0 + r, X = tx0 + cl;      // padded coords (pad=1)
    unsigned char v = 0;
    if (Y >= 1 && Y <= HH && X >= 1 && X <= WW) {
      float val = src[(Y - 1) * WW + (X - 1)];
      float q = rintf((val * 255.0f) / 16.0f);   // matches jnp.round(x*255/16), RNE
      q = fminf(fmaxf(q, 0.0f), 16.0f);
      v = (unsigned char)(int)q;
    }
    tile[i] = v;
  }
  __syncthreads();
  int ty = threadIdx.x >> 4, tx = threadIdx.x & 15;
  int oy = ty0 + ty, ox = tx0 + tx;
  if (oy >= HM || ox >= HM) return;
  unsigned long long w0 = 0, w1 = 0, w2 = 0;
  for (int dy = 0; dy < 11; dy++) {
    #pragma unroll
    for (int dx = 0; dx < 11; dx++) {
      int b = tile[(ty + dy) * 26 + tx + dx];
      unsigned long long inc = 1ull << ((b & 7) * 8);
      if (b < 8) w0 += inc;
      else if (b < 16) w1 += inc;
      else w2 += inc;
    }
  }
  int best = -1, bestb = 0;
  #pragma unroll
  for (int b = 0; b < 17; b++) {
    int cnt;
    if (b < 8)       cnt = (int)((w0 >> (b * 8)) & 0xff);
    else if (b < 16) cnt = (int)((w1 >> ((b - 8) * 8)) & 0xff);
    else             cnt = (int)(w2 & 0xff);
    if (cnt > best) { best = cnt; bestb = b; }   // strict > keeps lowest bin on tie
  }
  hmode[bc * HM * HM + oy * HM + ox] = (unsigned char)bestb;
}

// ---------------- K3: fused conv1+maxleaky + grouped conv2 + minleaky + downgrade ----------------
__global__ __launch_bounds__(256) void k_prepare(const unsigned char* __restrict__ hmode,
                                                 const float* __restrict__ w1,
                                                 const float* __restrict__ b1,
                                                 const float* __restrict__ w2,
                                                 const float* __restrict__ b2,
                                                 const float* __restrict__ down_k,
                                                 const float* __restrict__ down_b,
                                                 float* __restrict__ d1) {
  int bc = blockIdx.y;
  int b  = bc >> 6;
  int c  = bc & 63;
  int pix = blockIdx.x * 256 + threadIdx.x;
  if (pix >= 168 * 168) return;
  int oy = pix / 168, ox = pix % 168;
  int c0 = (c >> 1) << 1;
  float w1a0 = w1[c0 * 3], w1a1 = w1[c0 * 3 + 1], w1a2 = w1[c0 * 3 + 2], b1a = b1[c0];
  float w1b0 = w1[(c0 + 1) * 3], w1b1 = w1[(c0 + 1) * 3 + 1], w1b2 = w1[(c0 + 1) * 3 + 2], b1b = b1[c0 + 1];
  float w2a = w2[c * 2], w2b = w2[c * 2 + 1], b2c = b2[c];
  float kb = *down_b;
  const unsigned char* h0p = hmode + (b * 3 + 0) * HM * HM;
  const unsigned char* h1p = hmode + (b * 3 + 1) * HM * HM;
  const unsigned char* h2p = hmode + (b * 3 + 2) * HM * HM;
  float acc = 0.0f;
  #pragma unroll
  for (int ky = 0; ky < 3; ky++) {
    int y = 3 * oy - 1 + ky;
    if (y < 0 || y >= HM) continue;
    #pragma unroll
    for (int kx = 0; kx < 3; kx++) {
      int xx = 3 * ox - 1 + kx;
      if (xx < 0 || xx >= HM) continue;
      int o = y * HM + xx;
      float hh0 = h0p[o] * (1.0f / 16.0f);
      float hh1 = h1p[o] * (1.0f / 16.0f);
      float hh2 = h2p[o] * (1.0f / 16.0f);
      float a0 = w1a0 * hh0 + w1a1 * hh1 + w1a2 * hh2 + b1a;
      float a1 = w1b0 * hh0 + w1b1 * hh1 + w1b2 * hh2 + b1b;
      a0 = (a0 <= 0.1f) ? a0 : 0.1f + 0.01f * (a0 - 0.1f);
      a1 = (a1 <= 0.1f) ? a1 : 0.1f + 0.01f * (a1 - 0.1f);
      float v = w2a * a0 + w2b * a1 + b2c;
      v = (v >= 0.1f) ? v : 0.1f + 0.01f * (v - 0.1f);
      acc += down_k[ky * 3 + kx] * v;
    }
  }
  float r = acc + kb;
  r = (r >= 0.0f) ? r : 0.01f * r;
  d1[bc * 168 * 168 + pix] = r;
}

// ---------------- K4: generic downgrade (3x3 s3 p1 shared) + leaky ----------------
__global__ __launch_bounds__(256) void k_down(const float* __restrict__ din,
                                              float* __restrict__ dout,
                                              const float* __restrict__ down_k,
                                              const float* __restrict__ down_b,
                                              int S, int So) {
  int bc = blockIdx.y;
  int pix = blockIdx.x * 256 + threadIdx.x;
  if (pix >= So * So) return;
  int oy = pix / So, ox = pix % So;
  const float* p = din + bc * S * S;
  float acc = 0.0f;
  #pragma unroll
  for (int ky = 0; ky < 3; ky++) {
    int y = 3 * oy - 1 + ky;
    if (y < 0 || y >= S) continue;
    #pragma unroll
    for (int kx = 0; kx < 3; kx++) {
      int xx = 3 * ox - 1 + kx;
      if (xx < 0 || xx >= S) continue;
      acc += down_k[ky * 3 + kx] * p[y * S + xx];
    }
  }
  float r = acc + *down_b;
  r = (r >= 0.0f) ? r : 0.01f * r;
  dout[bc * So * So + pix] = r;
}

// ---------------- K_lut: packed bilinear LUT {asfloat(y0), w} per level/coord ----------------
__global__ __launch_bounds__(256) void k_lut(float2* __restrict__ lutpk) {
  int idx = blockIdx.x * 256 + threadIdx.x;   // 5*512
  if (idx >= 5 * 512) return;
  int lvl = idx >> 9, Y = idx & 511;
  const int Ls[5] = {168, 56, 19, 7, 3};
  int L = Ls[lvl];
  float f = (Y + 0.5f) * ((float)L / 512.0f) - 0.5f;
  f = fminf(fmaxf(f, 0.0f), (float)(L - 1));
  int y0 = (int)f;
  float w = f - (float)y0;
  lutpk[idx] = make_float2(__int_as_float(y0), w);
}

// ---------------- K5: composite 5-level resize+conv+BN+leaky+sum ----------------
// out[y][x] = sum_r conv5x(xrow[r], kappa[y][r])[x]; kappa folds the bilinear
// y-weights into per-(row, coarse-row) 5-tap kernels. kap layout uses row
// stride 20 floats: bank = (20y+5rr+kx) mod 32; collisions need 4dy+drr ≡ 0
// mod 32 -> only y<->y+8 (2-way, free). The R3 stride-32 layout was a 16-way
// write / 4-way read conflict (3e7 cycles, ~22% of kernel time).
__global__ __launch_bounds__(256, 4) void k_score(const float* __restrict__ d1,
                                                  const float* __restrict__ d2,
                                                  const float* __restrict__ d3,
                                                  const float* __restrict__ d4,
                                                  const float* __restrict__ d5,
                                                  const float2* __restrict__ lutpk,
                                                  const float* __restrict__ interp_k,
                                                  const float* __restrict__ interp_b,
                                                  const float* __restrict__ i_gamma,
                                                  const float* __restrict__ i_beta,
                                                  const float* __restrict__ i_mean,
                                                  const float* __restrict__ i_var,
                                                  float* __restrict__ score) {
  __shared__ float xrow[24 * 68];      // [r][xx], stride 68 (272B, 16B-aligned rows)
  __shared__ float kap[64 * 20];       // [y][rr*5+kx], stride 20 (conflict-free)
  __shared__ int   abase[64];          // a0base(y) - r0

  int bc = blockIdx.y;
  int c  = bc & 63;
  int tile = blockIdx.x;
  int tyi = tile >> 3, txi = tile & 7;
  int ty0 = tyi * 64, tx0 = txi * 64;
  float K[25];
  #pragma unroll
  for (int i = 0; i < 25; i++)
    K[i] = __int_as_float(__builtin_amdgcn_readfirstlane(__float_as_int(interp_k[i])));
  float ib  = __int_as_float(__builtin_amdgcn_readfirstlane(__float_as_int(*interp_b)));
  float isc = i_gamma[c] * rsqrtf(i_var[c] + 1e-5f);
  float ibe = i_beta[c] - i_mean[c] * isc;
  int tid = threadIdx.x;
  int oyl = (tid >> 4) << 2, oxl = (tid & 15) << 2;  // 4x4 px per thread
  float acc[4][4];
  #pragma unroll
  for (int i = 0; i < 4; i++)
    #pragma unroll
    for (int j = 0; j < 4; j++) acc[i][j] = 0.0f;

  const float* dls[5] = {d1, d2, d3, d4, d5};
  const int Ls[5]  = {168, 56, 19, 7, 3};
  const int RLs[5] = {24, 10, 5, 3, 3};

  auto fillLevel = [&](int l) {
    int L = Ls[l], RR = RLs[l];
    const float* dp = dls[l] + bc * L * L;
    const float2* lp = lutpk + (l << 9);
    int Ylo = max(ty0 - 2, 0);
    int r0 = __float_as_int(lp[Ylo].x);
    // kappa: thread tid -> (y = tid>>2, rrel = tid&3)
    {
      int y = tid >> 2, rr = tid & 3;
      int Y = ty0 + y;
      float kv0 = 0.0f, kv1 = 0.0f, kv2 = 0.0f, kv3 = 0.0f, kv4 = 0.0f;
      int ab = -1;
      #pragma unroll
      for (int ky = 0; ky < 5; ky++) {
        int yy = Y + ky - 2;
        if (yy >= 0 && yy < 512) {
          float2 pk = lp[yy];
          int a0 = __float_as_int(pk.x);
          float wv = pk.y;
          if (ab < 0) ab = a0;           // first valid ky has the min a0 (monotone)
          float cf = 0.0f;
          if (a0 - ab == rr)     cf += 1.0f - wv;
          if (a0 + 1 - ab == rr) cf += wv;
          kv0 += cf * K[ky * 5 + 0];
          kv1 += cf * K[ky * 5 + 1];
          kv2 += cf * K[ky * 5 + 2];
          kv3 += cf * K[ky * 5 + 3];
          kv4 += cf * K[ky * 5 + 4];
        }
      }
      float* kp = &kap[y * 20 + rr * 5];
      kp[0] = kv0; kp[1] = kv1; kp[2] = kv2; kp[3] = kv3; kp[4] = kv4;
      if (rr == 0) abase[y] = ab - r0;
    }
    // xrow: x-upsample coarse rows, zero outside image columns
    for (int i = tid; i < RR * 68; i += 256) {
      int r = i / 68, xx = i - r * 68;
      int X = tx0 - 2 + xx;
      float v = 0.0f;
      if (X >= 0 && X < 512) {
        float2 pk = lp[X];
        int ix = __float_as_int(pk.x);
        float wx = pk.y;
        int gr = min(r0 + r, L - 1);
        const float* rp = dp + gr * L + ix;
        float v0 = rp[0], v1 = rp[1];    // v1 unused when wx==0 (clamp)
        v = v0 + wx * (v1 - v0);
      }
      xrow[r * 68 + xx] = v;
    }
  };

  auto convAcc = [&](int rspan, int rlim) {
    #pragma unroll
    for (int i = 0; i < 4; i++) {
      int y = oyl + i;
      int ab = abase[y];
      float t0 = 0.0f, t1 = 0.0f, t2v = 0.0f, t3 = 0.0f;
      for (int rr = 0; rr < rspan; rr++) {
        int row = min(ab + rr, rlim);    // kappa==0 whenever clamp engages
        const float* xp = &xrow[row * 68 + oxl];
        float4 A = *(const float4*)xp;
        float4 B = *(const float4*)(xp + 4);
        const float* kp = &kap[y * 20 + rr * 5];
        float k0 = kp[0], k1 = kp[1], k2 = kp[2], k3 = kp[3], k4 = kp[4];
        t0  += k0 * A.x + k1 * A.y + k2 * A.z + k3 * A.w + k4 * B.x;
        t1  += k0 * A.y + k1 * A.z + k2 * A.w + k3 * B.x + k4 * B.y;
        t2v += k0 * A.z + k1 * A.w + k2 * B.x + k3 * B.y + k4 * B.z;
        t3  += k0 * A.w + k1 * B.x + k2 * B.y + k3 * B.z + k4 * B.w;
      }
      float tv[4] = {t0, t1, t2v, t3};
      #pragma unroll
      for (int j = 0; j < 4; j++) {
        float v = (tv[j] + ib) * isc + ibe;
        v = (v >= 0.0f) ? v : 0.01f * v;
        acc[i][j] += v;
      }
    }
  };

  #pragma unroll 1
  for (int l = 0; l < 5; l++) {
    if (l) __syncthreads();              // conv(l-1) done with LDS
    fillLevel(l);
    __syncthreads();
    if (l == 0) convAcc(4, RLs[0] - 1);
    else        convAcc(3, RLs[l] - 1);
  }

  float* op = score + bc * 512 * 512;
  #pragma unroll
  for (int i = 0; i < 4; i++) {
    int Y = ty0 + oyl + i;
    float4 vv = make_float4(acc[i][0], acc[i][1], acc[i][2], acc[i][3]);
    *(float4*)(op + Y * 512 + tx0 + oxl) = vv;
  }
}

// ---------------- K6: 3x ft as a full-row-width vertical pipeline ----------------
// (unchanged from R2 — see that round's notes; next optimization target)
__global__ __launch_bounds__(256, 2) void k_ft_pipe(const float* __restrict__ s_in,
                                                    float* __restrict__ s_out,
                                                    const float* __restrict__ ft_gamma,
                                                    const float* __restrict__ ft_beta,
                                                    const float* __restrict__ ft_mean,
                                                    const float* __restrict__ ft_var,
                                                    const float* __restrict__ ft_k,
                                                    const float* __restrict__ ft_b,
                                                    const float* __restrict__ emph_w) {
  __shared__ float ring2[12 * 512];   // U2 rows (affine-applied), per-thread columns only
  __shared__ float ring3[12 * 512];   // U3 rows
  __shared__ float brow1[528];        // C1 row, idx = col + 6, pads [0..5],[518..523] = 0
  __shared__ float brow2[528];
  __shared__ float brow3[528];

  const int bc = blockIdx.y;          // 0..127
  const int c  = bc & 63;
  const int R0 = blockIdx.x << 7;     // band start row (0,128,256,384)
  const int mstart = R0 - 15;

  const float sc  = ft_gamma[c] * rsqrtf(ft_var[c] + 1e-5f);
  const float fk = *ft_k, fb = *ft_b;
  const float Aff = sc * fk;
  const float Cc  = (ft_beta[c] - ft_mean[c] * sc) * fk + fb;
  const float w   = emph_w[c];
  const float opw = 1.0f + w;
  const float okw = w * (1.0f / 121.0f);

  const int tid = threadIdx.x;
  const int x0  = tid << 1;

  const float* sp = s_in + ((size_t)bc << 18) + x0;
  float*       op = s_out + ((size_t)bc << 18) + x0;

  // zero the horizontal pads once (ordered before first read by the in-loop barrier)
  if (tid < 12) {
    int p = (tid < 6) ? tid : (512 + tid);
    brow1[p] = 0.0f; brow2[p] = 0.0f; brow3[p] = 0.0f;
  }

  auto ldraw = [&](int row) -> v2f {
    int rc = min(max(row, 0), 511);        // clamp keeps the access in-bounds
    return *(const v2f*)(sp + ((size_t)rc << 9));
  };

  // two 11-sums (cols x0, x0+1) from brow window [x0-6 .. x0+7]
  auto rowsum = [&](const float* b) -> v2f {
    const float* p = b + x0;               // brow idx x0 == col x0-6
    v2f w0 = *(const v2f*)(p);
    v2f w1 = *(const v2f*)(p + 2);
    v2f w2 = *(const v2f*)(p + 4);
    v2f w3 = *(const v2f*)(p + 6);
    v2f w4 = *(const v2f*)(p + 8);
    v2f w5 = *(const v2f*)(p + 10);
    v2f w6 = *(const v2f*)(p + 12);
    float smid = ((w1.x + w1.y) + (w2.x + w2.y)) +
                 ((w3.x + w3.y) + (w4.x + w4.y)) + (w5.x + w5.y);   // cols x0-4..x0+5
    v2f r;
    r.x = smid + w0.y;   // + col x0-5
    r.y = smid + w6.x;   // + col x0+6
    return r;
  };

  v2f cs1 = (v2f)0.0f, cs2 = (v2f)0.0f, cs3 = (v2f)0.0f;
  v2f out1p = (v2f)0.0f, out2p = (v2f)0.0f;   // S1/S2 rows produced last step (raw)

  int m = mstart;
  v2f gf = ldraw(m);          // row m      (stage-1 front)
  v2f go = ldraw(m - 11);     // row m-11   (stage-1 subtract)
  v2f gc = ldraw(m - 5);      // row m-5    (stage-1 center)
  int sw = 0;                 // i % 12

  #pragma unroll 1
  for (int i = 0; i < 160; ++i, ++m) {
    // software prefetch for next step (hides HBM/L2 latency across the two barriers)
    v2f gf_n = ldraw(m + 1);
    v2f go_n = ldraw(m - 10);
    v2f gc_n = ldraw(m - 4);

    int swn = (sw + 1 == 12) ? 0 : sw + 1;        // slot holding row (front-11)
    int swc = (sw + 7 >= 12) ? sw - 5 : sw + 7;   // slot holding row (front-5)

    // ---------------- W phase: advance column sums, publish C rows ----------------
    {  // stage 1: front row m
      v2f u1f = (m >= 0 && m < 512) ? (gf * Aff + Cc) : (v2f)0.0f;
      int r = m - 11;
      v2f u1o = (r >= mstart && r >= 0 && r < 512) ? (go * Aff + Cc) : (v2f)0.0f;
      cs1 += u1f - u1o;                            // cs1 = colsum at row m-5
      *(v2f*)(brow1 + 6 + x0) = cs1;
    }
    {  // stage 2: front row m-6 (consumes out1p = S1(m-6))
      v2f u2s = out1p * Aff + Cc;
      *(v2f*)(ring2 + sw * 512 + x0) = u2s;
      int rf = m - 6;
      v2f u2f = (rf >= 0 && rf < 512) ? u2s : (v2f)0.0f;
      int r = m - 17;
      v2f u2or = *(const v2f*)(ring2 + swn * 512 + x0);
      v2f u2o = (r >= mstart - 6 && r >= 0 && r < 512) ? u2or : (v2f)0.0f;
      cs2 += u2f - u2o;                            // cs2 = colsum at row m-11
      *(v2f*)(brow2 + 6 + x0) = cs2;
    }
    {  // stage 3: front row m-12 (consumes out2p = S2(m-12))
      v2f u3s = out2p * Aff + Cc;
      *(v2f*)(ring3 + sw * 512 + x0) = u3s;
      int rf = m - 12;
      v2f u3f = (rf >= 0 && rf < 512) ? u3s : (v2f)0.0f;
      int r = m - 23;
      v2f u3or = *(const v2f*)(ring3 + swn * 512 + x0);
      v2f u3o = (r >= mstart - 12 && r >= 0 && r < 512) ? u3or : (v2f)0.0f;
      cs3 += u3f - u3o;                            // cs3 = colsum at row m-17
      *(v2f*)(brow3 + 6 + x0) = cs3;
    }
    __syncthreads();
    // ---------------- R phase: horizontal 11-sums, emit stage outputs ----------------
    {  // S1(m-5)
      int rc1 = m - 5;
      v2f u1c = (rc1 >= 0 && rc1 < 512) ? (gc * Aff + Cc) : (v2f)0.0f;
      v2f B1 = rowsum(brow1);
      out1p = u1c * opw - B1 * okw;
    }
    {  // S2(m-11)
      int rc2 = m - 11;
      v2f u2cr = *(const v2f*)(ring2 + swc * 512 + x0);
      v2f u2c = (rc2 >= mstart - 6 && rc2 >= 0 && rc2 < 512) ? u2cr : (v2f)0.0f;
      v2f B2 = rowsum(brow2);
      out2p = u2c * opw - B2 * okw;
    }
    {  // S3(m-17) -> global
      int rc3 = m - 17;
      v2f u3cr = *(const v2f*)(ring3 + swc * 512 + x0);
      v2f u3c = (rc3 >= mstart - 12 && rc3 >= 0 && rc3 < 512) ? u3cr : (v2f)0.0f;
      v2f B3 = rowsum(brow3);
      v2f o3 = u3c * opw - B3 * okw;
      if (i >= 32)
        *(v2f*)(op + ((size_t)(m - 17) << 9)) = o3;   // rows R0 .. R0+127
    }
    __syncthreads();
    gf = gf_n; go = go_n; gc = gc_n;
    sw = swn;
  }
}

extern "C" void kernel_launch(void* const* d_in, const int* in_sizes, int n_in,
                              void* d_out, int out_size, void* d_ws, size_t ws_size,
                              hipStream_t stream) {
  const float* x        = (const float*)d_in[0];
  const float* w1       = (const float*)d_in[1];
  const float* b1       = (const float*)d_in[2];
  const float* w2       = (const float*)d_in[3];
  const float* b2       = (const float*)d_in[4];
  const float* down_k   = (const float*)d_in[5];
  const float* down_b   = (const float*)d_in[6];
  const float* ft_gamma = (const float*)d_in[7];
  const float* ft_beta  = (const float*)d_in[8];
  const float* ft_mean  = (const float*)d_in[9];
  const float* ft_var   = (const float*)d_in[10];
  const float* ft_k     = (const float*)d_in[11];
  const float* ft_b     = (const float*)d_in[12];
  const float* emph_w   = (const float*)d_in[13];
  const float* interp_k = (const float*)d_in[14];
  const float* interp_b = (const float*)d_in[15];
  const float* i_gamma  = (const float*)d_in[16];
  const float* i_beta   = (const float*)d_in[17];
  const float* i_mean   = (const float*)d_in[18];
  const float* i_var    = (const float*)d_in[19];
  float* out = (float*)d_out;                    // [2,64,512,512]

  char* ws = (char*)d_ws;
  size_t off = 0;
  auto alloc = [&](size_t bytes) { size_t r = off; off += (bytes + 255) & ~(size_t)255; return r; };
  unsigned char* hmode = (unsigned char*)(ws + alloc((size_t)NB * CIN * HM * HM));
  float* d1 = (float*)(ws + alloc((size_t)NB * C2 * 168 * 168 * 4));
  float* d2 = (float*)(ws + alloc((size_t)NB * C2 * 56 * 56 * 4));
  float* d3 = (float*)(ws + alloc((size_t)NB * C2 * 19 * 19 * 4));
  float* d4 = (float*)(ws + alloc((size_t)NB * C2 * 7 * 7 * 4));
  float* d5 = (float*)(ws + alloc((size_t)NB * C2 * 3 * 3 * 4));
  float* s0 = (float*)(ws + alloc((size_t)NB * C2 * 512 * 512 * 4));  // pre-ft score
  float2* lutpk = (float2*)(ws + alloc((size_t)5 * 512 * 8));

  k_mode<<<dim3(32, 32, NB * CIN), 256, 0, stream>>>(x, hmode);
  k_lut<<<10, 256, 0, stream>>>(lutpk);
  k_prepare<<<dim3((168 * 168 + 255) / 256, NB * C2), 256, 0, stream>>>(
      hmode, w1, b1, w2, b2, down_k, down_b, d1);
  k_down<<<dim3((56 * 56 + 255) / 256, NB * C2), 256, 0, stream>>>(d1, d2, down_k, down_b, 168, 56);
  k_down<<<dim3((19 * 19 + 255) / 256, NB * C2), 256, 0, stream>>>(d2, d3, down_k, down_b, 56, 19);
  k_down<<<dim3((7 * 7 + 255) / 256, NB * C2), 256, 0, stream>>>(d3, d4, down_k, down_b, 19, 7);
  k_down<<<dim3((3 * 3 + 255) / 256, NB * C2), 256, 0, stream>>>(d4, d5, down_k, down_b, 7, 3);
  k_score<<<dim3(64, NB * C2), 256, 0, stream>>>(d1, d2, d3, d4, d5, lutpk,
                                                 interp_k, interp_b,
                                                 i_gamma, i_beta, i_mean, i_var, s0);
  k_ft_pipe<<<dim3(4, NB * C2), 256, 0, stream>>>(s0, out, ft_gamma, ft_beta, ft_mean,
                                                  ft_var, ft_k, ft_b, emph_w);
}

// Round 5
// 549.531 us; speedup vs baseline: 1.5355x; 1.0492x over previous
//
#include <hip/hip_runtime.h>

#define NB 2
#define CIN 3
#define HH 512
#define WW 512
#define C2 64
#define HM 504   // mode-pool output size

typedef float v2f  __attribute__((ext_vector_type(2)));
typedef float v2fu __attribute__((ext_vector_type(2), aligned(4)));

// ---------------- K2: quantize (inline) + mode pool 11x11 -> u8 [2,3,504,504] ----------------
__global__ __launch_bounds__(256) void k_mode(const float* __restrict__ x,
                                              unsigned char* __restrict__ hmode) {
  __shared__ unsigned char tile[26 * 26];
  int bc  = blockIdx.z;
  int ty0 = blockIdx.y * 16, tx0 = blockIdx.x * 16;
  const float* src = x + (size_t)bc * HH * WW;
  for (int i = threadIdx.x; i < 26 * 26; i += 256) {
    int r = i / 26, cl = i % 26;
    int Y = ty0 + r, X = tx0 + cl;      // padded coords (pad=1)
    unsigned char v = 0;
    if (Y >= 1 && Y <= HH && X >= 1 && X <= WW) {
      float val = src[(Y - 1) * WW + (X - 1)];
      float q = rintf((val * 255.0f) / 16.0f);   // matches jnp.round(x*255/16), RNE
      q = fminf(fmaxf(q, 0.0f), 16.0f);
      v = (unsigned char)(int)q;
    }
    tile[i] = v;
  }
  __syncthreads();
  int ty = threadIdx.x >> 4, tx = threadIdx.x & 15;
  int oy = ty0 + ty, ox = tx0 + tx;
  if (oy >= HM || ox >= HM) return;
  unsigned long long w0 = 0, w1 = 0, w2 = 0;
  for (int dy = 0; dy < 11; dy++) {
    #pragma unroll
    for (int dx = 0; dx < 11; dx++) {
      int b = tile[(ty + dy) * 26 + tx + dx];
      unsigned long long inc = 1ull << ((b & 7) * 8);
      if (b < 8) w0 += inc;
      else if (b < 16) w1 += inc;
      else w2 += inc;
    }
  }
  int best = -1, bestb = 0;
  #pragma unroll
  for (int b = 0; b < 17; b++) {
    int cnt;
    if (b < 8)       cnt = (int)((w0 >> (b * 8)) & 0xff);
    else if (b < 16) cnt = (int)((w1 >> ((b - 8) * 8)) & 0xff);
    else             cnt = (int)(w2 & 0xff);
    if (cnt > best) { best = cnt; bestb = b; }   // strict > keeps lowest bin on tie
  }
  hmode[bc * HM * HM + oy * HM + ox] = (unsigned char)bestb;
}

// ---------------- K3: fused conv1+maxleaky + grouped conv2 + minleaky + downgrade ----------------
__global__ __launch_bounds__(256) void k_prepare(const unsigned char* __restrict__ hmode,
                                                 const float* __restrict__ w1,
                                                 const float* __restrict__ b1,
                                                 const float* __restrict__ w2,
                                                 const float* __restrict__ b2,
                                                 const float* __restrict__ down_k,
                                                 const float* __restrict__ down_b,
                                                 float* __restrict__ d1) {
  int bc = blockIdx.y;
  int b  = bc >> 6;
  int c  = bc & 63;
  int pix = blockIdx.x * 256 + threadIdx.x;
  if (pix >= 168 * 168) return;
  int oy = pix / 168, ox = pix % 168;
  int c0 = (c >> 1) << 1;
  float w1a0 = w1[c0 * 3], w1a1 = w1[c0 * 3 + 1], w1a2 = w1[c0 * 3 + 2], b1a = b1[c0];
  float w1b0 = w1[(c0 + 1) * 3], w1b1 = w1[(c0 + 1) * 3 + 1], w1b2 = w1[(c0 + 1) * 3 + 2], b1b = b1[c0 + 1];
  float w2a = w2[c * 2], w2b = w2[c * 2 + 1], b2c = b2[c];
  float kb = *down_b;
  const unsigned char* h0p = hmode + (b * 3 + 0) * HM * HM;
  const unsigned char* h1p = hmode + (b * 3 + 1) * HM * HM;
  const unsigned char* h2p = hmode + (b * 3 + 2) * HM * HM;
  float acc = 0.0f;
  #pragma unroll
  for (int ky = 0; ky < 3; ky++) {
    int y = 3 * oy - 1 + ky;
    if (y < 0 || y >= HM) continue;
    #pragma unroll
    for (int kx = 0; kx < 3; kx++) {
      int xx = 3 * ox - 1 + kx;
      if (xx < 0 || xx >= HM) continue;
      int o = y * HM + xx;
      float hh0 = h0p[o] * (1.0f / 16.0f);
      float hh1 = h1p[o] * (1.0f / 16.0f);
      float hh2 = h2p[o] * (1.0f / 16.0f);
      float a0 = w1a0 * hh0 + w1a1 * hh1 + w1a2 * hh2 + b1a;
      float a1 = w1b0 * hh0 + w1b1 * hh1 + w1b2 * hh2 + b1b;
      a0 = (a0 <= 0.1f) ? a0 : 0.1f + 0.01f * (a0 - 0.1f);
      a1 = (a1 <= 0.1f) ? a1 : 0.1f + 0.01f * (a1 - 0.1f);
      float v = w2a * a0 + w2b * a1 + b2c;
      v = (v >= 0.1f) ? v : 0.1f + 0.01f * (v - 0.1f);
      acc += down_k[ky * 3 + kx] * v;
    }
  }
  float r = acc + kb;
  r = (r >= 0.0f) ? r : 0.01f * r;
  d1[bc * 168 * 168 + pix] = r;
}

// ---------------- K4: generic downgrade (3x3 s3 p1 shared) + leaky ----------------
__global__ __launch_bounds__(256) void k_down(const float* __restrict__ din,
                                              float* __restrict__ dout,
                                              const float* __restrict__ down_k,
                                              const float* __restrict__ down_b,
                                              int S, int So) {
  int bc = blockIdx.y;
  int pix = blockIdx.x * 256 + threadIdx.x;
  if (pix >= So * So) return;
  int oy = pix / So, ox = pix % So;
  const float* p = din + bc * S * S;
  float acc = 0.0f;
  #pragma unroll
  for (int ky = 0; ky < 3; ky++) {
    int y = 3 * oy - 1 + ky;
    if (y < 0 || y >= S) continue;
    #pragma unroll
    for (int kx = 0; kx < 3; kx++) {
      int xx = 3 * ox - 1 + kx;
      if (xx < 0 || xx >= S) continue;
      acc += down_k[ky * 3 + kx] * p[y * S + xx];
    }
  }
  float r = acc + *down_b;
  r = (r >= 0.0f) ? r : 0.01f * r;
  dout[bc * So * So + pix] = r;
}

// ---------------- K_lut: packed bilinear LUT {asfloat(y0), w} per level/coord ----------------
__global__ __launch_bounds__(256) void k_lut(float2* __restrict__ lutpk) {
  int idx = blockIdx.x * 256 + threadIdx.x;   // 5*512
  if (idx >= 5 * 512) return;
  int lvl = idx >> 9, Y = idx & 511;
  const int Ls[5] = {168, 56, 19, 7, 3};
  int L = Ls[lvl];
  float f = (Y + 0.5f) * ((float)L / 512.0f) - 0.5f;
  f = fminf(fmaxf(f, 0.0f), (float)(L - 1));
  int y0 = (int)f;
  float w = f - (float)y0;
  lutpk[idx] = make_float2(__int_as_float(y0), w);
}

// ---------------- K5: composite 5-level resize+conv+BN+leaky+sum ----------------
// out[y][x] = sum_r conv5x(xrow[r], kappa[y][r])[x]; kappa folds the bilinear
// y-weights into per-(row, coarse-row) 5-tap kernels. kap layout uses row
// stride 20 floats (conflict-free; see R4 notes).
__global__ __launch_bounds__(256, 4) void k_score(const float* __restrict__ d1,
                                                  const float* __restrict__ d2,
                                                  const float* __restrict__ d3,
                                                  const float* __restrict__ d4,
                                                  const float* __restrict__ d5,
                                                  const float2* __restrict__ lutpk,
                                                  const float* __restrict__ interp_k,
                                                  const float* __restrict__ interp_b,
                                                  const float* __restrict__ i_gamma,
                                                  const float* __restrict__ i_beta,
                                                  const float* __restrict__ i_mean,
                                                  const float* __restrict__ i_var,
                                                  float* __restrict__ score) {
  __shared__ float xrow[24 * 68];      // [r][xx], stride 68 (272B, 16B-aligned rows)
  __shared__ float kap[64 * 20];       // [y][rr*5+kx], stride 20 (conflict-free)
  __shared__ int   abase[64];          // a0base(y) - r0

  int bc = blockIdx.y;
  int c  = bc & 63;
  int tile = blockIdx.x;
  int tyi = tile >> 3, txi = tile & 7;
  int ty0 = tyi * 64, tx0 = txi * 64;
  float K[25];
  #pragma unroll
  for (int i = 0; i < 25; i++)
    K[i] = __int_as_float(__builtin_amdgcn_readfirstlane(__float_as_int(interp_k[i])));
  float ib  = __int_as_float(__builtin_amdgcn_readfirstlane(__float_as_int(*interp_b)));
  float isc = i_gamma[c] * rsqrtf(i_var[c] + 1e-5f);
  float ibe = i_beta[c] - i_mean[c] * isc;
  int tid = threadIdx.x;
  int oyl = (tid >> 4) << 2, oxl = (tid & 15) << 2;  // 4x4 px per thread
  float acc[4][4];
  #pragma unroll
  for (int i = 0; i < 4; i++)
    #pragma unroll
    for (int j = 0; j < 4; j++) acc[i][j] = 0.0f;

  const float* dls[5] = {d1, d2, d3, d4, d5};
  const int Ls[5]  = {168, 56, 19, 7, 3};
  const int RLs[5] = {24, 10, 5, 3, 3};

  auto fillLevel = [&](int l) {
    int L = Ls[l], RR = RLs[l];
    const float* dp = dls[l] + bc * L * L;
    const float2* lp = lutpk + (l << 9);
    int Ylo = max(ty0 - 2, 0);
    int r0 = __float_as_int(lp[Ylo].x);
    // kappa: thread tid -> (y = tid>>2, rrel = tid&3)
    {
      int y = tid >> 2, rr = tid & 3;
      int Y = ty0 + y;
      float kv0 = 0.0f, kv1 = 0.0f, kv2 = 0.0f, kv3 = 0.0f, kv4 = 0.0f;
      int ab = -1;
      #pragma unroll
      for (int ky = 0; ky < 5; ky++) {
        int yy = Y + ky - 2;
        if (yy >= 0 && yy < 512) {
          float2 pk = lp[yy];
          int a0 = __float_as_int(pk.x);
          float wv = pk.y;
          if (ab < 0) ab = a0;           // first valid ky has the min a0 (monotone)
          float cf = 0.0f;
          if (a0 - ab == rr)     cf += 1.0f - wv;
          if (a0 + 1 - ab == rr) cf += wv;
          kv0 += cf * K[ky * 5 + 0];
          kv1 += cf * K[ky * 5 + 1];
          kv2 += cf * K[ky * 5 + 2];
          kv3 += cf * K[ky * 5 + 3];
          kv4 += cf * K[ky * 5 + 4];
        }
      }
      float* kp = &kap[y * 20 + rr * 5];
      kp[0] = kv0; kp[1] = kv1; kp[2] = kv2; kp[3] = kv3; kp[4] = kv4;
      if (rr == 0) abase[y] = ab - r0;
    }
    // xrow: x-upsample coarse rows, zero outside image columns
    for (int i = tid; i < RR * 68; i += 256) {
      int r = i / 68, xx = i - r * 68;
      int X = tx0 - 2 + xx;
      float v = 0.0f;
      if (X >= 0 && X < 512) {
        float2 pk = lp[X];
        int ix = __float_as_int(pk.x);
        float wx = pk.y;
        int gr = min(r0 + r, L - 1);
        const float* rp = dp + gr * L + ix;
        float v0 = rp[0], v1 = rp[1];    // v1 unused when wx==0 (clamp)
        v = v0 + wx * (v1 - v0);
      }
      xrow[r * 68 + xx] = v;
    }
  };

  auto convAcc = [&](int rspan, int rlim) {
    #pragma unroll
    for (int i = 0; i < 4; i++) {
      int y = oyl + i;
      int ab = abase[y];
      float t0 = 0.0f, t1 = 0.0f, t2v = 0.0f, t3 = 0.0f;
      for (int rr = 0; rr < rspan; rr++) {
        int row = min(ab + rr, rlim);    // kappa==0 whenever clamp engages
        const float* xp = &xrow[row * 68 + oxl];
        float4 A = *(const float4*)xp;
        float4 B = *(const float4*)(xp + 4);
        const float* kp = &kap[y * 20 + rr * 5];
        float k0 = kp[0], k1 = kp[1], k2 = kp[2], k3 = kp[3], k4 = kp[4];
        t0  += k0 * A.x + k1 * A.y + k2 * A.z + k3 * A.w + k4 * B.x;
        t1  += k0 * A.y + k1 * A.z + k2 * A.w + k3 * B.x + k4 * B.y;
        t2v += k0 * A.z + k1 * A.w + k2 * B.x + k3 * B.y + k4 * B.z;
        t3  += k0 * A.w + k1 * B.x + k2 * B.y + k3 * B.z + k4 * B.w;
      }
      float tv[4] = {t0, t1, t2v, t3};
      #pragma unroll
      for (int j = 0; j < 4; j++) {
        float v = (tv[j] + ib) * isc + ibe;
        v = (v >= 0.0f) ? v : 0.01f * v;
        acc[i][j] += v;
      }
    }
  };

  #pragma unroll 1
  for (int l = 0; l < 5; l++) {
    if (l) __syncthreads();              // conv(l-1) done with LDS
    fillLevel(l);
    __syncthreads();
    if (l == 0) convAcc(4, RLs[0] - 1);
    else        convAcc(3, RLs[l] - 1);
  }

  float* op = score + bc * 512 * 512;
  #pragma unroll
  for (int i = 0; i < 4; i++) {
    int Y = ty0 + oyl + i;
    float4 vv = make_float4(acc[i][0], acc[i][1], acc[i][2], acc[i][3]);
    *(float4*)(op + Y * 512 + tx0 + oxl) = vv;
  }
}

// ---------------- K6: 3x ft vertical pipeline, v2 ----------------
// v2 changes vs R2-R4 version:
//  * rings are REGISTERS: they were only ever read at the writing thread's own
//    x0 (thread-private). Main loop unrolled by the ring period (12) so all
//    ring indices are compile-time (rule: runtime-indexed reg arrays spill).
//  * ONE barrier per iteration: brow double-buffered [2]; W(i) writes buf[i&1],
//    barrier, R(i) reads buf[i&1]. W(i+2)'s overwrite of buf[i&1] is ordered
//    after R(i) by iteration i+1's barrier.
//  * front-row global prefetch 2-deep (the only HBM-cold read; go/gc re-read
//    L2-hot rows).
//  * LDS 55KB -> 12.3KB: occupancy 2 -> 3-4 blocks/CU (VGPR-bound).
// Warm-up masking identical to v1; iters 160 -> 168 (14x12), store guarded
// to i in [32,160).
__global__ __launch_bounds__(256, 3) void k_ft_pipe(const float* __restrict__ s_in,
                                                    float* __restrict__ s_out,
                                                    const float* __restrict__ ft_gamma,
                                                    const float* __restrict__ ft_beta,
                                                    const float* __restrict__ ft_mean,
                                                    const float* __restrict__ ft_var,
                                                    const float* __restrict__ ft_k,
                                                    const float* __restrict__ ft_b,
                                                    const float* __restrict__ emph_w) {
  __shared__ float brow1[2][524];     // col c at idx c+6; pads [0..5],[518..523] = 0
  __shared__ float brow2[2][524];
  __shared__ float brow3[2][524];

  const int bc = blockIdx.y;          // 0..127
  const int c  = bc & 63;
  const int R0 = blockIdx.x << 7;     // band start row (0,128,256,384)
  const int mstart = R0 - 15;

  const float sc  = ft_gamma[c] * rsqrtf(ft_var[c] + 1e-5f);
  const float fk = *ft_k, fb = *ft_b;
  const float Aff = sc * fk;
  const float Cc  = (ft_beta[c] - ft_mean[c] * sc) * fk + fb;
  const float w   = emph_w[c];
  const float opw = 1.0f + w;
  const float okw = w * (1.0f / 121.0f);

  const int tid = threadIdx.x;
  const int x0  = tid << 1;

  const float* sp = s_in + ((size_t)bc << 18) + x0;
  float*       op = s_out + ((size_t)bc << 18) + x0;

  // zero the horizontal pads (both buffers); ordered before first read by the
  // first in-loop barrier
  if (tid < 72) {
    int a = tid / 24, pb = (tid / 12) & 1, e = tid % 12;
    int idx = (e < 6) ? e : (512 + e);
    float* base = (a == 0) ? &brow1[pb][0] : (a == 1) ? &brow2[pb][0] : &brow3[pb][0];
    base[idx] = 0.0f;
  }

  auto ldraw = [&](int row) -> v2f {
    int rc = min(max(row, 0), 511);        // clamp keeps the access in-bounds
    return *(const v2f*)(sp + ((size_t)rc << 9));
  };

  // two 11-sums (cols x0, x0+1) from brow window [x0-6 .. x0+7]
  auto rowsum = [&](const float* b) -> v2f {
    const float* p = b + x0;               // brow idx x0 == col x0-6
    v2f w0 = *(const v2f*)(p);
    v2f w1 = *(const v2f*)(p + 2);
    v2f w2 = *(const v2f*)(p + 4);
    v2f w3 = *(const v2f*)(p + 6);
    v2f w4 = *(const v2f*)(p + 8);
    v2f w5 = *(const v2f*)(p + 10);
    v2f w6 = *(const v2f*)(p + 12);
    float smid = ((w1.x + w1.y) + (w2.x + w2.y)) +
                 ((w3.x + w3.y) + (w4.x + w4.y)) + (w5.x + w5.y);   // cols x0-4..x0+5
    v2f r;
    r.x = smid + w0.y;   // + col x0-5
    r.y = smid + w6.x;   // + col x0+6
    return r;
  };

  v2f cs1 = (v2f)0.0f, cs2 = (v2f)0.0f, cs3 = (v2f)0.0f;
  v2f out1p = (v2f)0.0f, out2p = (v2f)0.0f;   // S1/S2 rows produced last step (raw)

  v2f r2[12], r3[12];                  // register rings (compile-time indexed)
  #pragma unroll
  for (int k = 0; k < 12; k++) { r2[k] = (v2f)0.0f; r3[k] = (v2f)0.0f; }

  v2f gf  = ldraw(mstart);            // row m       (stage-1 front)
  v2f gfa = ldraw(mstart + 1);        // row m+1     (front prefetch, depth 2)
  v2f go  = ldraw(mstart - 11);       // row m-11    (stage-1 subtract, L2-hot)
  v2f gc  = ldraw(mstart - 5);        // row m-5     (stage-1 center, L2-hot)

  #pragma unroll 1
  for (int ii = 0; ii < 14; ++ii) {
    #pragma unroll
    for (int j = 0; j < 12; ++j) {
      const int i = ii * 12 + j;
      const int m = mstart + i;
      // prefetch: front 2-deep (HBM-cold), others 1-deep (L2-hot re-reads)
      v2f gf_n2 = ldraw(m + 2);
      v2f go_n  = ldraw(m - 10);
      v2f gc_n  = ldraw(m - 4);

      const int p = j & 1;

      // ---------------- W phase: advance column sums, publish C rows ----------------
      {  // stage 1: front row m
        v2f u1f = (m >= 0 && m < 512) ? (gf * Aff + Cc) : (v2f)0.0f;
        int r = m - 11;
        v2f u1o = (r >= mstart && r >= 0 && r < 512) ? (go * Aff + Cc) : (v2f)0.0f;
        cs1 += u1f - u1o;                            // cs1 = colsum at row m-5
        *(v2f*)(&brow1[p][6 + x0]) = cs1;
      }
      {  // stage 2: front row m-6 (consumes out1p = S1(m-6))
        v2f u2s = out1p * Aff + Cc;
        v2f u2or = r2[(j + 1) % 12];                 // value from 11 iters ago
        r2[j] = u2s;
        int rf = m - 6;
        v2f u2f = (rf >= 0 && rf < 512) ? u2s : (v2f)0.0f;
        int r = m - 17;
        v2f u2o = (r >= mstart - 6 && r >= 0 && r < 512) ? u2or : (v2f)0.0f;
        cs2 += u2f - u2o;                            // cs2 = colsum at row m-11
        *(v2f*)(&brow2[p][6 + x0]) = cs2;
      }
      {  // stage 3: front row m-12 (consumes out2p = S2(m-12))
        v2f u3s = out2p * Aff + Cc;
        v2f u3or = r3[(j + 1) % 12];
        r3[j] = u3s;
        int rf = m - 12;
        v2f u3f = (rf >= 0 && rf < 512) ? u3s : (v2f)0.0f;
        int r = m - 23;
        v2f u3o = (r >= mstart - 12 && r >= 0 && r < 512) ? u3or : (v2f)0.0f;
        cs3 += u3f - u3o;                            // cs3 = colsum at row m-17
        *(v2f*)(&brow3[p][6 + x0]) = cs3;
      }
      __syncthreads();                               // brow[p] published
      // ---------------- R phase: horizontal 11-sums, emit stage outputs ----------------
      {  // S1(m-5)
        int rc1 = m - 5;
        v2f u1c = (rc1 >= 0 && rc1 < 512) ? (gc * Aff + Cc) : (v2f)0.0f;
        v2f B1 = rowsum(&brow1[p][0]);
        out1p = u1c * opw - B1 * okw;
      }
      {  // S2(m-11)
        int rc2 = m - 11;
        v2f u2cr = r2[(j + 7) % 12];                 // value from 5 iters ago
        v2f u2c = (rc2 >= mstart - 6 && rc2 >= 0 && rc2 < 512) ? u2cr : (v2f)0.0f;
        v2f B2 = rowsum(&brow2[p][0]);
        out2p = u2c * opw - B2 * okw;
      }
      {  // S3(m-17) -> global
        int rc3 = m - 17;
        v2f u3cr = r3[(j + 7) % 12];
        v2f u3c = (rc3 >= mstart - 12 && rc3 >= 0 && rc3 < 512) ? u3cr : (v2f)0.0f;
        v2f B3 = rowsum(&brow3[p][0]);
        v2f o3 = u3c * opw - B3 * okw;
        if (i >= 32 && i < 160)
          *(v2f*)(op + ((size_t)(m - 17) << 9)) = o3;   // rows R0 .. R0+127
      }
      // no second barrier: next iter writes brow[p^1]; brow[p] is rewritten
      // two iters from now, ordered after this R by the next iter's barrier.
      gf = gfa; gfa = gf_n2; go = go_n; gc = gc_n;
    }
  }
}

extern "C" void kernel_launch(void* const* d_in, const int* in_sizes, int n_in,
                              void* d_out, int out_size, void* d_ws, size_t ws_size,
                              hipStream_t stream) {
  const float* x        = (const float*)d_in[0];
  const float* w1       = (const float*)d_in[1];
  const float* b1       = (const float*)d_in[2];
  const float* w2       = (const float*)d_in[3];
  const float* b2       = (const float*)d_in[4];
  const float* down_k   = (const float*)d_in[5];
  const float* down_b   = (const float*)d_in[6];
  const float* ft_gamma = (const float*)d_in[7];
  const float* ft_beta  = (const float*)d_in[8];
  const float* ft_mean  = (const float*)d_in[9];
  const float* ft_var   = (const float*)d_in[10];
  const float* ft_k     = (const float*)d_in[11];
  const float* ft_b     = (const float*)d_in[12];
  const float* emph_w   = (const float*)d_in[13];
  const float* interp_k = (const float*)d_in[14];
  const float* interp_b = (const float*)d_in[15];
  const float* i_gamma  = (const float*)d_in[16];
  const float* i_beta   = (const float*)d_in[17];
  const float* i_mean   = (const float*)d_in[18];
  const float* i_var    = (const float*)d_in[19];
  float* out = (float*)d_out;                    // [2,64,512,512]

  char* ws = (char*)d_ws;
  size_t off = 0;
  auto alloc = [&](size_t bytes) { size_t r = off; off += (bytes + 255) & ~(size_t)255; return r; };
  unsigned char* hmode = (unsigned char*)(ws + alloc((size_t)NB * CIN * HM * HM));
  float* d1 = (float*)(ws + alloc((size_t)NB * C2 * 168 * 168 * 4));
  float* d2 = (float*)(ws + alloc((size_t)NB * C2 * 56 * 56 * 4));
  float* d3 = (float*)(ws + alloc((size_t)NB * C2 * 19 * 19 * 4));
  float* d4 = (float*)(ws + alloc((size_t)NB * C2 * 7 * 7 * 4));
  float* d5 = (float*)(ws + alloc((size_t)NB * C2 * 3 * 3 * 4));
  float* s0 = (float*)(ws + alloc((size_t)NB * C2 * 512 * 512 * 4));  // pre-ft score
  float2* lutpk = (float2*)(ws + alloc((size_t)5 * 512 * 8));

  k_mode<<<dim3(32, 32, NB * CIN), 256, 0, stream>>>(x, hmode);
  k_lut<<<10, 256, 0, stream>>>(lutpk);
  k_prepare<<<dim3((168 * 168 + 255) / 256, NB * C2), 256, 0, stream>>>(
      hmode, w1, b1, w2, b2, down_k, down_b, d1);
  k_down<<<dim3((56 * 56 + 255) / 256, NB * C2), 256, 0, stream>>>(d1, d2, down_k, down_b, 168, 56);
  k_down<<<dim3((19 * 19 + 255) / 256, NB * C2), 256, 0, stream>>>(d2, d3, down_k, down_b, 56, 19);
  k_down<<<dim3((7 * 7 + 255) / 256, NB * C2), 256, 0, stream>>>(d3, d4, down_k, down_b, 19, 7);
  k_down<<<dim3((3 * 3 + 255) / 256, NB * C2), 256, 0, stream>>>(d4, d5, down_k, down_b, 7, 3);
  k_score<<<dim3(64, NB * C2), 256, 0, stream>>>(d1, d2, d3, d4, d5, lutpk,
                                                 interp_k, interp_b,
                                                 i_gamma, i_beta, i_mean, i_var, s0);
  k_ft_pipe<<<dim3(4, NB * C2), 256, 0, stream>>>(s0, out, ft_gamma, ft_beta, ft_mean,
                                                  ft_var, ft_k, ft_b, emph_w);
}

// Round 6
// 544.261 us; speedup vs baseline: 1.5504x; 1.0097x over previous
//
#include <hip/hip_runtime.h>

#define NB 2
#define CIN 3
#define HH 512
#define WW 512
#define C2 64
#define HM 504   // mode-pool output size

typedef float v2f  __attribute__((ext_vector_type(2)));
typedef float v2fu __attribute__((ext_vector_type(2), aligned(4)));

// ---------------- K2: quantize (inline) + mode pool 11x11 -> u8 [2,3,504,504] ----------------
__global__ __launch_bounds__(256) void k_mode(const float* __restrict__ x,
                                              unsigned char* __restrict__ hmode) {
  __shared__ unsigned char tile[26 * 26];
  int bc  = blockIdx.z;
  int ty0 = blockIdx.y * 16, tx0 = blockIdx.x * 16;
  const float* src = x + (size_t)bc * HH * WW;
  for (int i = threadIdx.x; i < 26 * 26; i += 256) {
    int r = i / 26, cl = i % 26;
    int Y = ty0 + r, X = tx0 + cl;      // padded coords (pad=1)
    unsigned char v = 0;
    if (Y >= 1 && Y <= HH && X >= 1 && X <= WW) {
      float val = src[(Y - 1) * WW + (X - 1)];
      float q = rintf((val * 255.0f) / 16.0f);   // matches jnp.round(x*255/16), RNE
      q = fminf(fmaxf(q, 0.0f), 16.0f);
      v = (unsigned char)(int)q;
    }
    tile[i] = v;
  }
  __syncthreads();
  int ty = threadIdx.x >> 4, tx = threadIdx.x & 15;
  int oy = ty0 + ty, ox = tx0 + tx;
  if (oy >= HM || ox >= HM) return;
  unsigned long long w0 = 0, w1 = 0, w2 = 0;
  for (int dy = 0; dy < 11; dy++) {
    #pragma unroll
    for (int dx = 0; dx < 11; dx++) {
      int b = tile[(ty + dy) * 26 + tx + dx];
      unsigned long long inc = 1ull << ((b & 7) * 8);
      if (b < 8) w0 += inc;
      else if (b < 16) w1 += inc;
      else w2 += inc;
    }
  }
  int best = -1, bestb = 0;
  #pragma unroll
  for (int b = 0; b < 17; b++) {
    int cnt;
    if (b < 8)       cnt = (int)((w0 >> (b * 8)) & 0xff);
    else if (b < 16) cnt = (int)((w1 >> ((b - 8) * 8)) & 0xff);
    else             cnt = (int)(w2 & 0xff);
    if (cnt > best) { best = cnt; bestb = b; }   // strict > keeps lowest bin on tie
  }
  hmode[bc * HM * HM + oy * HM + ox] = (unsigned char)bestb;
}

// ---------------- K3: fused conv1+maxleaky + grouped conv2 + minleaky + downgrade ----------------
__global__ __launch_bounds__(256) void k_prepare(const unsigned char* __restrict__ hmode,
                                                 const float* __restrict__ w1,
                                                 const float* __restrict__ b1,
                                                 const float* __restrict__ w2,
                                                 const float* __restrict__ b2,
                                                 const float* __restrict__ down_k,
                                                 const float* __restrict__ down_b,
                                                 float* __restrict__ d1) {
  int bc = blockIdx.y;
  int b  = bc >> 6;
  int c  = bc & 63;
  int pix = blockIdx.x * 256 + threadIdx.x;
  if (pix >= 168 * 168) return;
  int oy = pix / 168, ox = pix % 168;
  int c0 = (c >> 1) << 1;
  float w1a0 = w1[c0 * 3], w1a1 = w1[c0 * 3 + 1], w1a2 = w1[c0 * 3 + 2], b1a = b1[c0];
  float w1b0 = w1[(c0 + 1) * 3], w1b1 = w1[(c0 + 1) * 3 + 1], w1b2 = w1[(c0 + 1) * 3 + 2], b1b = b1[c0 + 1];
  float w2a = w2[c * 2], w2b = w2[c * 2 + 1], b2c = b2[c];
  float kb = *down_b;
  const unsigned char* h0p = hmode + (b * 3 + 0) * HM * HM;
  const unsigned char* h1p = hmode + (b * 3 + 1) * HM * HM;
  const unsigned char* h2p = hmode + (b * 3 + 2) * HM * HM;
  float acc = 0.0f;
  #pragma unroll
  for (int ky = 0; ky < 3; ky++) {
    int y = 3 * oy - 1 + ky;
    if (y < 0 || y >= HM) continue;
    #pragma unroll
    for (int kx = 0; kx < 3; kx++) {
      int xx = 3 * ox - 1 + kx;
      if (xx < 0 || xx >= HM) continue;
      int o = y * HM + xx;
      float hh0 = h0p[o] * (1.0f / 16.0f);
      float hh1 = h1p[o] * (1.0f / 16.0f);
      float hh2 = h2p[o] * (1.0f / 16.0f);
      float a0 = w1a0 * hh0 + w1a1 * hh1 + w1a2 * hh2 + b1a;
      float a1 = w1b0 * hh0 + w1b1 * hh1 + w1b2 * hh2 + b1b;
      a0 = (a0 <= 0.1f) ? a0 : 0.1f + 0.01f * (a0 - 0.1f);
      a1 = (a1 <= 0.1f) ? a1 : 0.1f + 0.01f * (a1 - 0.1f);
      float v = w2a * a0 + w2b * a1 + b2c;
      v = (v >= 0.1f) ? v : 0.1f + 0.01f * (v - 0.1f);
      acc += down_k[ky * 3 + kx] * v;
    }
  }
  float r = acc + kb;
  r = (r >= 0.0f) ? r : 0.01f * r;
  d1[bc * 168 * 168 + pix] = r;
}

// ---------------- K4: generic downgrade (3x3 s3 p1 shared) + leaky ----------------
__global__ __launch_bounds__(256) void k_down(const float* __restrict__ din,
                                              float* __restrict__ dout,
                                              const float* __restrict__ down_k,
                                              const float* __restrict__ down_b,
                                              int S, int So) {
  int bc = blockIdx.y;
  int pix = blockIdx.x * 256 + threadIdx.x;
  if (pix >= So * So) return;
  int oy = pix / So, ox = pix % So;
  const float* p = din + bc * S * S;
  float acc = 0.0f;
  #pragma unroll
  for (int ky = 0; ky < 3; ky++) {
    int y = 3 * oy - 1 + ky;
    if (y < 0 || y >= S) continue;
    #pragma unroll
    for (int kx = 0; kx < 3; kx++) {
      int xx = 3 * ox - 1 + kx;
      if (xx < 0 || xx >= S) continue;
      acc += down_k[ky * 3 + kx] * p[y * S + xx];
    }
  }
  float r = acc + *down_b;
  r = (r >= 0.0f) ? r : 0.01f * r;
  dout[bc * So * So + pix] = r;
}

// ---------------- K_lut: packed bilinear LUT {asfloat(y0), w} per level/coord ----------------
__global__ __launch_bounds__(256) void k_lut(float2* __restrict__ lutpk) {
  int idx = blockIdx.x * 256 + threadIdx.x;   // 5*512
  if (idx >= 5 * 512) return;
  int lvl = idx >> 9, Y = idx & 511;
  const int Ls[5] = {168, 56, 19, 7, 3};
  int L = Ls[lvl];
  float f = (Y + 0.5f) * ((float)L / 512.0f) - 0.5f;
  f = fminf(fmaxf(f, 0.0f), (float)(L - 1));
  int y0 = (int)f;
  float w = f - (float)y0;
  lutpk[idx] = make_float2(__int_as_float(y0), w);
}

// ---------------- K5: composite 5-level resize+conv+BN+leaky+sum, v2 ----------------
// v2: 64x128 tiles, 4x8 px/thread (taps reused across 8 outputs -> LDS ops and
// aux VALU per pixel halve); kap packed at stride 36 floats/y, slot y*36+rr*8,
// read as b128+b32 (2 LDS ops vs 5 scalar). Bank audit: dy=4 -> 144 ≡ 16 mod 32,
// dy=8 -> 2-way (free); 16B alignment holds (144y+32rr bytes). xrow rows stride
// 132 floats (528B, 16B-aligned); cross-group alias worst-case 2-way.
__global__ __launch_bounds__(256, 4) void k_score(const float* __restrict__ d1,
                                                  const float* __restrict__ d2,
                                                  const float* __restrict__ d3,
                                                  const float* __restrict__ d4,
                                                  const float* __restrict__ d5,
                                                  const float2* __restrict__ lutpk,
                                                  const float* __restrict__ interp_k,
                                                  const float* __restrict__ interp_b,
                                                  const float* __restrict__ i_gamma,
                                                  const float* __restrict__ i_beta,
                                                  const float* __restrict__ i_mean,
                                                  const float* __restrict__ i_var,
                                                  float* __restrict__ score) {
  __shared__ float xrow[24 * 132];     // [r][xx], stride 132
  __shared__ float kap[64 * 36];       // [y][rr*8 + kx], 5 used per slot
  __shared__ int   abase[64];          // a0base(y) - r0

  int bc = blockIdx.y;
  int c  = bc & 63;
  int tile = blockIdx.x;               // 32 tiles: 8 y-tiles x 4 x-tiles
  int tyi = tile >> 2, txi = tile & 3;
  int ty0 = tyi * 64, tx0 = txi * 128;
  float K[25];
  #pragma unroll
  for (int i = 0; i < 25; i++)
    K[i] = __int_as_float(__builtin_amdgcn_readfirstlane(__float_as_int(interp_k[i])));
  float ib  = __int_as_float(__builtin_amdgcn_readfirstlane(__float_as_int(*interp_b)));
  float isc = i_gamma[c] * rsqrtf(i_var[c] + 1e-5f);
  float ibe = i_beta[c] - i_mean[c] * isc;
  int tid = threadIdx.x;
  int oyl = (tid >> 4) << 2, oxl = (tid & 15) << 3;  // 4x8 px per thread
  float acc[4][8];
  #pragma unroll
  for (int i = 0; i < 4; i++)
    #pragma unroll
    for (int j = 0; j < 8; j++) acc[i][j] = 0.0f;

  const float* dls[5] = {d1, d2, d3, d4, d5};
  const int Ls[5]  = {168, 56, 19, 7, 3};
  const int RLs[5] = {24, 10, 5, 3, 3};

  auto fillLevel = [&](int l) {
    int L = Ls[l], RR = RLs[l];
    const float* dp = dls[l] + bc * L * L;
    const float2* lp = lutpk + (l << 9);
    int Ylo = max(ty0 - 2, 0);
    int r0 = __float_as_int(lp[Ylo].x);
    // kappa: thread tid -> (y = tid>>2, rrel = tid&3)
    {
      int y = tid >> 2, rr = tid & 3;
      int Y = ty0 + y;
      float kv0 = 0.0f, kv1 = 0.0f, kv2 = 0.0f, kv3 = 0.0f, kv4 = 0.0f;
      int ab = -1;
      #pragma unroll
      for (int ky = 0; ky < 5; ky++) {
        int yy = Y + ky - 2;
        if (yy >= 0 && yy < 512) {
          float2 pk = lp[yy];
          int a0 = __float_as_int(pk.x);
          float wv = pk.y;
          if (ab < 0) ab = a0;           // first valid ky has the min a0 (monotone)
          float cf = 0.0f;
          if (a0 - ab == rr)     cf += 1.0f - wv;
          if (a0 + 1 - ab == rr) cf += wv;
          kv0 += cf * K[ky * 5 + 0];
          kv1 += cf * K[ky * 5 + 1];
          kv2 += cf * K[ky * 5 + 2];
          kv3 += cf * K[ky * 5 + 3];
          kv4 += cf * K[ky * 5 + 4];
        }
      }
      float* kp = &kap[y * 36 + rr * 8];
      kp[0] = kv0; kp[1] = kv1; kp[2] = kv2; kp[3] = kv3; kp[4] = kv4;
      if (rr == 0) abase[y] = ab - r0;
    }
    // xrow: x-upsample coarse rows, zero outside image columns
    for (int i = tid; i < RR * 132; i += 256) {
      int r = i / 132, xx = i - r * 132;
      int X = tx0 - 2 + xx;
      float v = 0.0f;
      if (X >= 0 && X < 512) {
        float2 pk = lp[X];
        int ix = __float_as_int(pk.x);
        float wx = pk.y;
        int gr = min(r0 + r, L - 1);
        const float* rp = dp + gr * L + ix;
        float v0 = rp[0], v1 = rp[1];    // v1 unused when wx==0 (clamp)
        v = v0 + wx * (v1 - v0);
      }
      xrow[r * 132 + xx] = v;
    }
  };

  auto convAcc = [&](int rspan, int rlim) {
    #pragma unroll
    for (int i = 0; i < 4; i++) {
      int y = oyl + i;
      int ab = abase[y];
      float t[8];
      #pragma unroll
      for (int j = 0; j < 8; j++) t[j] = 0.0f;
      for (int rr = 0; rr < rspan; rr++) {
        int row = min(ab + rr, rlim);    // kappa==0 whenever clamp engages
        const float* xp = &xrow[row * 132 + oxl];
        float4 A = *(const float4*)xp;
        float4 B = *(const float4*)(xp + 4);
        float4 Cx = *(const float4*)(xp + 8);
        const float* kp = &kap[y * 36 + rr * 8];
        float4 kk = *(const float4*)kp;
        float k4v = kp[4];
        float wnd[12] = {A.x, A.y, A.z, A.w, B.x, B.y, B.z, B.w, Cx.x, Cx.y, Cx.z, Cx.w};
        #pragma unroll
        for (int j = 0; j < 8; j++)
          t[j] += kk.x * wnd[j] + kk.y * wnd[j + 1] + kk.z * wnd[j + 2] +
                  kk.w * wnd[j + 3] + k4v * wnd[j + 4];
      }
      #pragma unroll
      for (int j = 0; j < 8; j++) {
        float v = (t[j] + ib) * isc + ibe;
        v = (v >= 0.0f) ? v : 0.01f * v;
        acc[i][j] += v;
      }
    }
  };

  #pragma unroll 1
  for (int l = 0; l < 5; l++) {
    if (l) __syncthreads();              // conv(l-1) done with LDS
    fillLevel(l);
    __syncthreads();
    if (l == 0) convAcc(4, RLs[0] - 1);
    else        convAcc(3, RLs[l] - 1);
  }

  float* op = score + bc * 512 * 512;
  #pragma unroll
  for (int i = 0; i < 4; i++) {
    int Y = ty0 + oyl + i;
    float* orow = op + Y * 512 + tx0 + oxl;
    *(float4*)(orow)     = make_float4(acc[i][0], acc[i][1], acc[i][2], acc[i][3]);
    *(float4*)(orow + 4) = make_float4(acc[i][4], acc[i][5], acc[i][6], acc[i][7]);
  }
}

// ---------------- K6: 3x ft vertical pipeline, v2 (unchanged from R5) ----------------
__global__ __launch_bounds__(256, 3) void k_ft_pipe(const float* __restrict__ s_in,
                                                    float* __restrict__ s_out,
                                                    const float* __restrict__ ft_gamma,
                                                    const float* __restrict__ ft_beta,
                                                    const float* __restrict__ ft_mean,
                                                    const float* __restrict__ ft_var,
                                                    const float* __restrict__ ft_k,
                                                    const float* __restrict__ ft_b,
                                                    const float* __restrict__ emph_w) {
  __shared__ float brow1[2][524];     // col c at idx c+6; pads [0..5],[518..523] = 0
  __shared__ float brow2[2][524];
  __shared__ float brow3[2][524];

  const int bc = blockIdx.y;          // 0..127
  const int c  = bc & 63;
  const int R0 = blockIdx.x << 7;     // band start row (0,128,256,384)
  const int mstart = R0 - 15;

  const float sc  = ft_gamma[c] * rsqrtf(ft_var[c] + 1e-5f);
  const float fk = *ft_k, fb = *ft_b;
  const float Aff = sc * fk;
  const float Cc  = (ft_beta[c] - ft_mean[c] * sc) * fk + fb;
  const float w   = emph_w[c];
  const float opw = 1.0f + w;
  const float okw = w * (1.0f / 121.0f);

  const int tid = threadIdx.x;
  const int x0  = tid << 1;

  const float* sp = s_in + ((size_t)bc << 18) + x0;
  float*       op = s_out + ((size_t)bc << 18) + x0;

  // zero the horizontal pads (both buffers); ordered before first read by the
  // first in-loop barrier
  if (tid < 72) {
    int a = tid / 24, pb = (tid / 12) & 1, e = tid % 12;
    int idx = (e < 6) ? e : (512 + e);
    float* base = (a == 0) ? &brow1[pb][0] : (a == 1) ? &brow2[pb][0] : &brow3[pb][0];
    base[idx] = 0.0f;
  }

  auto ldraw = [&](int row) -> v2f {
    int rc = min(max(row, 0), 511);        // clamp keeps the access in-bounds
    return *(const v2f*)(sp + ((size_t)rc << 9));
  };

  // two 11-sums (cols x0, x0+1) from brow window [x0-6 .. x0+7]
  auto rowsum = [&](const float* b) -> v2f {
    const float* p = b + x0;               // brow idx x0 == col x0-6
    v2f w0 = *(const v2f*)(p);
    v2f w1 = *(const v2f*)(p + 2);
    v2f w2 = *(const v2f*)(p + 4);
    v2f w3 = *(const v2f*)(p + 6);
    v2f w4 = *(const v2f*)(p + 8);
    v2f w5 = *(const v2f*)(p + 10);
    v2f w6 = *(const v2f*)(p + 12);
    float smid = ((w1.x + w1.y) + (w2.x + w2.y)) +
                 ((w3.x + w3.y) + (w4.x + w4.y)) + (w5.x + w5.y);   // cols x0-4..x0+5
    v2f r;
    r.x = smid + w0.y;   // + col x0-5
    r.y = smid + w6.x;   // + col x0+6
    return r;
  };

  v2f cs1 = (v2f)0.0f, cs2 = (v2f)0.0f, cs3 = (v2f)0.0f;
  v2f out1p = (v2f)0.0f, out2p = (v2f)0.0f;   // S1/S2 rows produced last step (raw)

  v2f r2[12], r3[12];                  // register rings (compile-time indexed)
  #pragma unroll
  for (int k = 0; k < 12; k++) { r2[k] = (v2f)0.0f; r3[k] = (v2f)0.0f; }

  v2f gf  = ldraw(mstart);            // row m       (stage-1 front)
  v2f gfa = ldraw(mstart + 1);        // row m+1     (front prefetch, depth 2)
  v2f go  = ldraw(mstart - 11);       // row m-11    (stage-1 subtract, L2-hot)
  v2f gc  = ldraw(mstart - 5);        // row m-5     (stage-1 center, L2-hot)

  #pragma unroll 1
  for (int ii = 0; ii < 14; ++ii) {
    #pragma unroll
    for (int j = 0; j < 12; ++j) {
      const int i = ii * 12 + j;
      const int m = mstart + i;
      // prefetch: front 2-deep (HBM-cold), others 1-deep (L2-hot re-reads)
      v2f gf_n2 = ldraw(m + 2);
      v2f go_n  = ldraw(m - 10);
      v2f gc_n  = ldraw(m - 4);

      const int p = j & 1;

      // ---------------- W phase: advance column sums, publish C rows ----------------
      {  // stage 1: front row m
        v2f u1f = (m >= 0 && m < 512) ? (gf * Aff + Cc) : (v2f)0.0f;
        int r = m - 11;
        v2f u1o = (r >= mstart && r >= 0 && r < 512) ? (go * Aff + Cc) : (v2f)0.0f;
        cs1 += u1f - u1o;                            // cs1 = colsum at row m-5
        *(v2f*)(&brow1[p][6 + x0]) = cs1;
      }
      {  // stage 2: front row m-6 (consumes out1p = S1(m-6))
        v2f u2s = out1p * Aff + Cc;
        v2f u2or = r2[(j + 1) % 12];                 // value from 11 iters ago
        r2[j] = u2s;
        int rf = m - 6;
        v2f u2f = (rf >= 0 && rf < 512) ? u2s : (v2f)0.0f;
        int r = m - 17;
        v2f u2o = (r >= mstart - 6 && r >= 0 && r < 512) ? u2or : (v2f)0.0f;
        cs2 += u2f - u2o;                            // cs2 = colsum at row m-11
        *(v2f*)(&brow2[p][6 + x0]) = cs2;
      }
      {  // stage 3: front row m-12 (consumes out2p = S2(m-12))
        v2f u3s = out2p * Aff + Cc;
        v2f u3or = r3[(j + 1) % 12];
        r3[j] = u3s;
        int rf = m - 12;
        v2f u3f = (rf >= 0 && rf < 512) ? u3s : (v2f)0.0f;
        int r = m - 23;
        v2f u3o = (r >= mstart - 12 && r >= 0 && r < 512) ? u3or : (v2f)0.0f;
        cs3 += u3f - u3o;                            // cs3 = colsum at row m-17
        *(v2f*)(&brow3[p][6 + x0]) = cs3;
      }
      __syncthreads();                               // brow[p] published
      // ---------------- R phase: horizontal 11-sums, emit stage outputs ----------------
      {  // S1(m-5)
        int rc1 = m - 5;
        v2f u1c = (rc1 >= 0 && rc1 < 512) ? (gc * Aff + Cc) : (v2f)0.0f;
        v2f B1 = rowsum(&brow1[p][0]);
        out1p = u1c * opw - B1 * okw;
      }
      {  // S2(m-11)
        int rc2 = m - 11;
        v2f u2cr = r2[(j + 7) % 12];                 // value from 5 iters ago
        v2f u2c = (rc2 >= mstart - 6 && rc2 >= 0 && rc2 < 512) ? u2cr : (v2f)0.0f;
        v2f B2 = rowsum(&brow2[p][0]);
        out2p = u2c * opw - B2 * okw;
      }
      {  // S3(m-17) -> global
        int rc3 = m - 17;
        v2f u3cr = r3[(j + 7) % 12];
        v2f u3c = (rc3 >= mstart - 12 && rc3 >= 0 && rc3 < 512) ? u3cr : (v2f)0.0f;
        v2f B3 = rowsum(&brow3[p][0]);
        v2f o3 = u3c * opw - B3 * okw;
        if (i >= 32 && i < 160)
          *(v2f*)(op + ((size_t)(m - 17) << 9)) = o3;   // rows R0 .. R0+127
      }
      // no second barrier: next iter writes brow[p^1]; brow[p] is rewritten
      // two iters from now, ordered after this R by the next iter's barrier.
      gf = gfa; gfa = gf_n2; go = go_n; gc = gc_n;
    }
  }
}

extern "C" void kernel_launch(void* const* d_in, const int* in_sizes, int n_in,
                              void* d_out, int out_size, void* d_ws, size_t ws_size,
                              hipStream_t stream) {
  const float* x        = (const float*)d_in[0];
  const float* w1       = (const float*)d_in[1];
  const float* b1       = (const float*)d_in[2];
  const float* w2       = (const float*)d_in[3];
  const float* b2       = (const float*)d_in[4];
  const float* down_k   = (const float*)d_in[5];
  const float* down_b   = (const float*)d_in[6];
  const float* ft_gamma = (const float*)d_in[7];
  const float* ft_beta  = (const float*)d_in[8];
  const float* ft_mean  = (const float*)d_in[9];
  const float* ft_var   = (const float*)d_in[10];
  const float* ft_k     = (const float*)d_in[11];
  const float* ft_b     = (const float*)d_in[12];
  const float* emph_w   = (const float*)d_in[13];
  const float* interp_k = (const float*)d_in[14];
  const float* interp_b = (const float*)d_in[15];
  const float* i_gamma  = (const float*)d_in[16];
  const float* i_beta   = (const float*)d_in[17];
  const float* i_mean   = (const float*)d_in[18];
  const float* i_var    = (const float*)d_in[19];
  float* out = (float*)d_out;                    // [2,64,512,512]

  char* ws = (char*)d_ws;
  size_t off = 0;
  auto alloc = [&](size_t bytes) { size_t r = off; off += (bytes + 255) & ~(size_t)255; return r; };
  unsigned char* hmode = (unsigned char*)(ws + alloc((size_t)NB * CIN * HM * HM));
  float* d1 = (float*)(ws + alloc((size_t)NB * C2 * 168 * 168 * 4));
  float* d2 = (float*)(ws + alloc((size_t)NB * C2 * 56 * 56 * 4));
  float* d3 = (float*)(ws + alloc((size_t)NB * C2 * 19 * 19 * 4));
  float* d4 = (float*)(ws + alloc((size_t)NB * C2 * 7 * 7 * 4));
  float* d5 = (float*)(ws + alloc((size_t)NB * C2 * 3 * 3 * 4));
  float* s0 = (float*)(ws + alloc((size_t)NB * C2 * 512 * 512 * 4));  // pre-ft score
  float2* lutpk = (float2*)(ws + alloc((size_t)5 * 512 * 8));

  k_mode<<<dim3(32, 32, NB * CIN), 256, 0, stream>>>(x, hmode);
  k_lut<<<10, 256, 0, stream>>>(lutpk);
  k_prepare<<<dim3((168 * 168 + 255) / 256, NB * C2), 256, 0, stream>>>(
      hmode, w1, b1, w2, b2, down_k, down_b, d1);
  k_down<<<dim3((56 * 56 + 255) / 256, NB * C2), 256, 0, stream>>>(d1, d2, down_k, down_b, 168, 56);
  k_down<<<dim3((19 * 19 + 255) / 256, NB * C2), 256, 0, stream>>>(d2, d3, down_k, down_b, 56, 19);
  k_down<<<dim3((7 * 7 + 255) / 256, NB * C2), 256, 0, stream>>>(d3, d4, down_k, down_b, 19, 7);
  k_down<<<dim3((3 * 3 + 255) / 256, NB * C2), 256, 0, stream>>>(d4, d5, down_k, down_b, 7, 3);
  k_score<<<dim3(32, NB * C2), 256, 0, stream>>>(d1, d2, d3, d4, d5, lutpk,
                                                 interp_k, interp_b,
                                                 i_gamma, i_beta, i_mean, i_var, s0);
  k_ft_pipe<<<dim3(4, NB * C2), 256, 0, stream>>>(s0, out, ft_gamma, ft_beta, ft_mean,
                                                  ft_var, ft_k, ft_b, emph_w);
}